// Round 1
// baseline (703.161 us; speedup 1.0000x reference)
//
#include <hip/hip_runtime.h>
#include <hip/hip_bf16.h>
#include <math.h>

// Problem constants (from reference)
#define NN 50000
#define EE 800000
#define HH 128
#define LL 3
#define CC 47

typedef _Float16 half8  __attribute__((ext_vector_type(8)));
typedef _Float16 half2v __attribute__((ext_vector_type(2)));
typedef float    f32x4  __attribute__((ext_vector_type(4)));

__device__ __forceinline__ f32x4 mfma16(half8 a, half8 b, f32x4 c) {
    return __builtin_amdgcn_mfma_f32_16x16x32_f16(a, b, c, 0, 0, 0);
}

// ---------------- CSR build ----------------
__global__ void k_count(const int* __restrict__ ei, int* __restrict__ deg) {
    int e = blockIdx.x * blockDim.x + threadIdx.x;
    if (e < EE) atomicAdd(&deg[ei[EE + e]], 1);
}

__global__ void k_scan(const int* __restrict__ deg, int* __restrict__ rowstart,
                       int* __restrict__ cursor) {
    __shared__ int ps[1024];
    const int t = threadIdx.x;
    const int CH = (NN + 1023) / 1024;  // 49
    const int base = t * CH;
    int s = 0;
    for (int j = 0; j < CH; ++j) {
        int idx = base + j;
        if (idx < NN) s += deg[idx];
    }
    ps[t] = s;
    __syncthreads();
    for (int off = 1; off < 1024; off <<= 1) {
        int v = (t >= off) ? ps[t - off] : 0;
        __syncthreads();
        if (t >= off) ps[t] += v;
        __syncthreads();
    }
    int run = ps[t] - s;  // exclusive prefix
    for (int j = 0; j < CH; ++j) {
        int idx = base + j;
        if (idx < NN) {
            rowstart[idx] = run;
            cursor[idx] = run;
            run += deg[idx];
        }
    }
}

__global__ void k_fill(const int* __restrict__ ei, int* __restrict__ cursor,
                       int* __restrict__ csr) {
    int e = blockIdx.x * blockDim.x + threadIdx.x;
    if (e < EE) {
        int d = ei[EE + e];
        int pos = atomicAdd(&cursor[d], 1);
        csr[pos] = ei[e];  // src
    }
}

// ---------------- prep: fp16 convert, weight transpose, BN fold ----------------
__global__ void k_prep(const float* __restrict__ x, const float* __restrict__ W1,
                       const float* __restrict__ W2, const float* __restrict__ lw1,
                       const float* __restrict__ lw2, const float* __restrict__ b1,
                       const float* __restrict__ gamma, const float* __restrict__ beta,
                       const float* __restrict__ bnm, const float* __restrict__ bnv,
                       _Float16* __restrict__ xh, _Float16* __restrict__ Wt1h,
                       _Float16* __restrict__ Wt2h, _Float16* __restrict__ lw1t,
                       _Float16* __restrict__ lw2t, float* __restrict__ A1f,
                       float* __restrict__ B1f) {
    long i = (long)blockIdx.x * blockDim.x + threadIdx.x;
    const long P0 = (long)NN * HH;        // x convert
    const long P1 = P0 + (long)LL * HH * HH;  // W1 transpose
    const long P2 = P1 + (long)LL * HH * HH;  // W2 transpose
    const long P3 = P2 + HH * HH;             // lw1 transpose
    const long P4 = P3 + 48 * HH;             // lw2 transpose (padded)
    const long P5 = P4 + LL * HH;             // BN fold
    if (i < P0) {
        xh[i] = (_Float16)x[i];
    } else if (i < P1) {
        long j = i - P0;
        int l = (int)(j / (HH * HH));
        int n = (int)((j / HH) % HH);
        int k = (int)(j % HH);
        Wt1h[l * HH * HH + n * HH + k] = (_Float16)W1[l * HH * HH + k * HH + n];
    } else if (i < P2) {
        long j = i - P1;
        int l = (int)(j / (HH * HH));
        int n = (int)((j / HH) % HH);
        int k = (int)(j % HH);
        Wt2h[l * HH * HH + n * HH + k] = (_Float16)W2[l * HH * HH + k * HH + n];
    } else if (i < P3) {
        long j = i - P2;
        int n = (int)(j / HH), k = (int)(j % HH);
        lw1t[n * HH + k] = (_Float16)lw1[k * HH + n];
    } else if (i < P4) {
        long j = i - P3;
        int n = (int)(j / HH), k = (int)(j % HH);
        lw2t[n * HH + k] = (_Float16)((n < CC) ? lw2[k * CC + n] : 0.f);
    } else if (i < P5) {
        long j = i - P4;
        float s = gamma[j] * rsqrtf(bnv[j] + 1e-5f);
        A1f[j] = s;
        B1f[j] = (b1[j] - bnm[j]) * s + beta[j];
    }
}

// ---------------- fused GIN layer: gather + GEMM1 + BN + relu + GEMM2 + relu ----------------
// Tile: 64 nodes per block, 256 threads (4 waves). Column-split GEMM: wave w owns cols 32w..32w+31.
// LDS: A-tile 64x136 fp16 (reused for Z), weights 128x136 fp16 (staged twice). 52.2 KB -> 3 blocks/CU.
__global__ __launch_bounds__(256) void k_layer(
    const _Float16* __restrict__ hin, _Float16* __restrict__ hout,
    const _Float16* __restrict__ Wt1, const _Float16* __restrict__ Wt2,
    const float* __restrict__ A1, const float* __restrict__ B1,
    const float* __restrict__ b2, const int* __restrict__ rowstart,
    const int* __restrict__ degs, const int* __restrict__ csr, int nn) {
    __shared__ _Float16 Ab[64 * 136];
    __shared__ _Float16 Ws[128 * 136];
    const int tid = threadIdx.x;
    const int wave = tid >> 6, lane = tid & 63;
    const int q = lane >> 4, l15 = lane & 15;
    const int tile0 = blockIdx.x * 64;

    // stage Wt1 -> LDS (stride 136, 16B aligned rows)
    {
        int r = tid >> 4;
        const int c = (tid & 15) * 8;
#pragma unroll
        for (int it = 0; it < 8; ++it, r += 16)
            *(half8*)(Ws + r * 136 + c) = *(const half8*)(Wt1 + r * 128 + c);
    }
    // gather: each wave handles 16 nodes; lane owns features 2*lane, 2*lane+1
    {
        for (int nl = 0; nl < 16; ++nl) {
            const int row = wave * 16 + nl;
            const int g = tile0 + row;
            float ax = 0.f, ay = 0.f;
            if (g < nn) {
                half2v hv = *(const half2v*)(hin + (size_t)g * 128 + lane * 2);
                ax = (float)hv.x;
                ay = (float)hv.y;
                const int e0 = rowstart[g];
                const int d = degs[g];
#pragma unroll 4
                for (int e = e0; e < e0 + d; ++e) {
                    int s = csr[e];
                    half2v v = *(const half2v*)(hin + (size_t)s * 128 + lane * 2);
                    ax += (float)v.x;
                    ay += (float)v.y;
                }
            }
            half2v o;
            o.x = (_Float16)ax;
            o.y = (_Float16)ay;
            *(half2v*)(Ab + row * 136 + lane * 2) = o;
        }
    }
    __syncthreads();

    // GEMM1: all 64 rows x 32 cols per wave
    f32x4 acc[4][2];
#pragma unroll
    for (int s = 0; s < 4; ++s)
#pragma unroll
        for (int t = 0; t < 2; ++t) acc[s][t] = (f32x4){0.f, 0.f, 0.f, 0.f};
#pragma unroll
    for (int kt = 0; kt < 4; ++kt) {
        const int ko = kt * 32 + q * 8;
        half8 a0 = *(const half8*)(Ab + (0 * 16 + l15) * 136 + ko);
        half8 a1 = *(const half8*)(Ab + (1 * 16 + l15) * 136 + ko);
        half8 a2 = *(const half8*)(Ab + (2 * 16 + l15) * 136 + ko);
        half8 a3 = *(const half8*)(Ab + (3 * 16 + l15) * 136 + ko);
        half8 bb0 = *(const half8*)(Ws + (wave * 32 + 0 * 16 + l15) * 136 + ko);
        half8 bb1 = *(const half8*)(Ws + (wave * 32 + 1 * 16 + l15) * 136 + ko);
        acc[0][0] = mfma16(a0, bb0, acc[0][0]);
        acc[1][0] = mfma16(a1, bb0, acc[1][0]);
        acc[2][0] = mfma16(a2, bb0, acc[2][0]);
        acc[3][0] = mfma16(a3, bb0, acc[3][0]);
        acc[0][1] = mfma16(a0, bb1, acc[0][1]);
        acc[1][1] = mfma16(a1, bb1, acc[1][1]);
        acc[2][1] = mfma16(a2, bb1, acc[2][1]);
        acc[3][1] = mfma16(a3, bb1, acc[3][1]);
    }
    __syncthreads();

    // stage Wt2
    {
        int r = tid >> 4;
        const int c = (tid & 15) * 8;
#pragma unroll
        for (int it = 0; it < 8; ++it, r += 16)
            *(half8*)(Ws + r * 136 + c) = *(const half8*)(Wt2 + r * 128 + c);
    }
    // epilogue1: folded BN + relu -> Z into Ab
#pragma unroll
    for (int t = 0; t < 2; ++t) {
        const int col = wave * 32 + t * 16 + l15;
        const float sc = A1[col], sh = B1[col];
#pragma unroll
        for (int s = 0; s < 4; ++s)
#pragma unroll
            for (int r = 0; r < 4; ++r) {
                const int row = s * 16 + q * 4 + r;
                float v = acc[s][t][r] * sc + sh;
                Ab[row * 136 + col] = (_Float16)fmaxf(v, 0.f);
            }
    }
    __syncthreads();

    // GEMM2
#pragma unroll
    for (int s = 0; s < 4; ++s)
#pragma unroll
        for (int t = 0; t < 2; ++t) acc[s][t] = (f32x4){0.f, 0.f, 0.f, 0.f};
#pragma unroll
    for (int kt = 0; kt < 4; ++kt) {
        const int ko = kt * 32 + q * 8;
        half8 a0 = *(const half8*)(Ab + (0 * 16 + l15) * 136 + ko);
        half8 a1 = *(const half8*)(Ab + (1 * 16 + l15) * 136 + ko);
        half8 a2 = *(const half8*)(Ab + (2 * 16 + l15) * 136 + ko);
        half8 a3 = *(const half8*)(Ab + (3 * 16 + l15) * 136 + ko);
        half8 bb0 = *(const half8*)(Ws + (wave * 32 + 0 * 16 + l15) * 136 + ko);
        half8 bb1 = *(const half8*)(Ws + (wave * 32 + 1 * 16 + l15) * 136 + ko);
        acc[0][0] = mfma16(a0, bb0, acc[0][0]);
        acc[1][0] = mfma16(a1, bb0, acc[1][0]);
        acc[2][0] = mfma16(a2, bb0, acc[2][0]);
        acc[3][0] = mfma16(a3, bb0, acc[3][0]);
        acc[0][1] = mfma16(a0, bb1, acc[0][1]);
        acc[1][1] = mfma16(a1, bb1, acc[1][1]);
        acc[2][1] = mfma16(a2, bb1, acc[2][1]);
        acc[3][1] = mfma16(a3, bb1, acc[3][1]);
    }
    // epilogue2: +b2, relu, store
#pragma unroll
    for (int t = 0; t < 2; ++t) {
        const int col = wave * 32 + t * 16 + l15;
        const float bb = b2[col];
#pragma unroll
        for (int s = 0; s < 4; ++s)
#pragma unroll
            for (int r = 0; r < 4; ++r) {
                const int row = s * 16 + q * 4 + r;
                const int g = tile0 + row;
                if (g < nn) {
                    float v = fmaxf(acc[s][t][r] + bb, 0.f);
                    hout[(size_t)g * 128 + col] = (_Float16)v;
                }
            }
    }
}

// ---------------- head: GEMM(lw1)+relu -> GEMM(lw2,47 pad 48) -> log_softmax ----------------
__global__ __launch_bounds__(256) void k_head(const _Float16* __restrict__ hin,
                                              const _Float16* __restrict__ lw1t,
                                              const _Float16* __restrict__ lw2t,
                                              const float* __restrict__ lb1,
                                              const float* __restrict__ lb2,
                                              float* __restrict__ out, int nn) {
    __shared__ _Float16 Ab[64 * 136];
    __shared__ _Float16 Ws[128 * 136];
    const int tid = threadIdx.x;
    const int wave = tid >> 6, lane = tid & 63;
    const int q = lane >> 4, l15 = lane & 15;
    const int tile0 = blockIdx.x * 64;

    // stage A rows (h3)
    {
        int r = tid >> 4;
        const int c = (tid & 15) * 8;
#pragma unroll
        for (int it = 0; it < 4; ++it, r += 16) {
            const int g = tile0 + r;
            half8 v = {0, 0, 0, 0, 0, 0, 0, 0};
            if (g < nn) v = *(const half8*)(hin + (size_t)g * 128 + c);
            *(half8*)(Ab + r * 136 + c) = v;
        }
    }
    // stage lw1t
    {
        int r = tid >> 4;
        const int c = (tid & 15) * 8;
#pragma unroll
        for (int it = 0; it < 8; ++it, r += 16)
            *(half8*)(Ws + r * 136 + c) = *(const half8*)(lw1t + r * 128 + c);
    }
    __syncthreads();

    // GEMM1
    f32x4 acc[4][2];
#pragma unroll
    for (int s = 0; s < 4; ++s)
#pragma unroll
        for (int t = 0; t < 2; ++t) acc[s][t] = (f32x4){0.f, 0.f, 0.f, 0.f};
#pragma unroll
    for (int kt = 0; kt < 4; ++kt) {
        const int ko = kt * 32 + q * 8;
        half8 a0 = *(const half8*)(Ab + (0 * 16 + l15) * 136 + ko);
        half8 a1 = *(const half8*)(Ab + (1 * 16 + l15) * 136 + ko);
        half8 a2 = *(const half8*)(Ab + (2 * 16 + l15) * 136 + ko);
        half8 a3 = *(const half8*)(Ab + (3 * 16 + l15) * 136 + ko);
        half8 bb0 = *(const half8*)(Ws + (wave * 32 + 0 * 16 + l15) * 136 + ko);
        half8 bb1 = *(const half8*)(Ws + (wave * 32 + 1 * 16 + l15) * 136 + ko);
        acc[0][0] = mfma16(a0, bb0, acc[0][0]);
        acc[1][0] = mfma16(a1, bb0, acc[1][0]);
        acc[2][0] = mfma16(a2, bb0, acc[2][0]);
        acc[3][0] = mfma16(a3, bb0, acc[3][0]);
        acc[0][1] = mfma16(a0, bb1, acc[0][1]);
        acc[1][1] = mfma16(a1, bb1, acc[1][1]);
        acc[2][1] = mfma16(a2, bb1, acc[2][1]);
        acc[3][1] = mfma16(a3, bb1, acc[3][1]);
    }
    __syncthreads();

    // stage lw2t (48 rows)
    {
        int r = tid >> 4;
        const int c = (tid & 15) * 8;
#pragma unroll
        for (int it = 0; it < 3; ++it, r += 16)
            *(half8*)(Ws + r * 136 + c) = *(const half8*)(lw2t + r * 128 + c);
    }
    // epilogue1: +lb1, relu -> Ab
#pragma unroll
    for (int t = 0; t < 2; ++t) {
        const int col = wave * 32 + t * 16 + l15;
        const float bb = lb1[col];
#pragma unroll
        for (int s = 0; s < 4; ++s)
#pragma unroll
            for (int r = 0; r < 4; ++r) {
                const int row = s * 16 + q * 4 + r;
                float v = fmaxf(acc[s][t][r] + bb, 0.f);
                Ab[row * 136 + col] = (_Float16)v;
            }
    }
    __syncthreads();

    // GEMM2: 48 cols, waves 0..2 take 16 cols each
    f32x4 acc2[4];
#pragma unroll
    for (int s = 0; s < 4; ++s) acc2[s] = (f32x4){0.f, 0.f, 0.f, 0.f};
    if (wave < 3) {
#pragma unroll
        for (int kt = 0; kt < 4; ++kt) {
            const int ko = kt * 32 + q * 8;
            half8 a0 = *(const half8*)(Ab + (0 * 16 + l15) * 136 + ko);
            half8 a1 = *(const half8*)(Ab + (1 * 16 + l15) * 136 + ko);
            half8 a2 = *(const half8*)(Ab + (2 * 16 + l15) * 136 + ko);
            half8 a3 = *(const half8*)(Ab + (3 * 16 + l15) * 136 + ko);
            half8 bb = *(const half8*)(Ws + (wave * 16 + l15) * 136 + ko);
            acc2[0] = mfma16(a0, bb, acc2[0]);
            acc2[1] = mfma16(a1, bb, acc2[1]);
            acc2[2] = mfma16(a2, bb, acc2[2]);
            acc2[3] = mfma16(a3, bb, acc2[3]);
        }
    }
    __syncthreads();  // all reads of Ab done before aliasing as float buffer

    float* Lb = (float*)Ab;  // 64 x 49 floats = 12.5 KB <= 17.4 KB
    if (wave < 3) {
        const int col = wave * 16 + l15;
        const float bb = (col < CC) ? lb2[col] : 0.f;
#pragma unroll
        for (int s = 0; s < 4; ++s)
#pragma unroll
            for (int r = 0; r < 4; ++r) {
                const int row = s * 16 + q * 4 + r;
                Lb[row * 49 + col] = acc2[s][r] + bb;
            }
    }
    __syncthreads();

    // log_softmax: one thread per row
    if (tid < 64) {
        const int g = tile0 + tid;
        if (g < nn) {
            float m = -1e30f;
            for (int c = 0; c < CC; ++c) m = fmaxf(m, Lb[tid * 49 + c]);
            float ssum = 0.f;
            for (int c = 0; c < CC; ++c) ssum += expf(Lb[tid * 49 + c] - m);
            const float ls = logf(ssum) + m;
            for (int c = 0; c < CC; ++c) out[(size_t)g * CC + c] = Lb[tid * 49 + c] - ls;
        }
    }
}

// ---------------- host ----------------
extern "C" void kernel_launch(void* const* d_in, const int* in_sizes, int n_in,
                              void* d_out, int out_size, void* d_ws, size_t ws_size,
                              hipStream_t stream) {
    const float* x     = (const float*)d_in[0];
    const int*   ei    = (const int*)d_in[1];
    const float* W1    = (const float*)d_in[2];
    const float* b1    = (const float*)d_in[3];
    const float* gamma = (const float*)d_in[4];
    const float* beta  = (const float*)d_in[5];
    const float* bnm   = (const float*)d_in[6];
    const float* bnv   = (const float*)d_in[7];
    const float* W2    = (const float*)d_in[8];
    const float* b2    = (const float*)d_in[9];
    const float* lw1   = (const float*)d_in[10];
    const float* lb1   = (const float*)d_in[11];
    const float* lw2   = (const float*)d_in[12];
    const float* lb2   = (const float*)d_in[13];
    float* out = (float*)d_out;

    char* p = (char*)d_ws;
    auto carve = [&](size_t bytes) -> char* {
        char* r = p;
        p += (bytes + 255) & ~(size_t)255;
        return r;
    };
    int* deg      = (int*)carve((size_t)NN * 4);
    int* rowstart = (int*)carve((size_t)NN * 4);
    int* cursor   = (int*)carve((size_t)NN * 4);
    int* csr      = (int*)carve((size_t)EE * 4);
    _Float16* Wt1h = (_Float16*)carve((size_t)LL * HH * HH * 2);
    _Float16* Wt2h = (_Float16*)carve((size_t)LL * HH * HH * 2);
    _Float16* lw1t = (_Float16*)carve((size_t)HH * HH * 2);
    _Float16* lw2t = (_Float16*)carve((size_t)48 * HH * 2);
    float* A1f = (float*)carve((size_t)LL * HH * 4);
    float* B1f = (float*)carve((size_t)LL * HH * 4);
    _Float16* xh  = (_Float16*)carve((size_t)NN * HH * 2);
    _Float16* hb0 = (_Float16*)carve((size_t)NN * HH * 2);
    _Float16* hb1 = (_Float16*)carve((size_t)NN * HH * 2);

    // CSR build
    hipMemsetAsync(deg, 0, (size_t)NN * 4, stream);
    k_count<<<(EE + 255) / 256, 256, 0, stream>>>(ei, deg);
    k_scan<<<1, 1024, 0, stream>>>(deg, rowstart, cursor);
    k_fill<<<(EE + 255) / 256, 256, 0, stream>>>(ei, cursor, csr);

    // prep
    const long total = (long)NN * HH + 2L * LL * HH * HH + (long)HH * HH + 48L * HH + (long)LL * HH;
    k_prep<<<(int)((total + 255) / 256), 256, 0, stream>>>(
        x, W1, W2, lw1, lw2, b1, gamma, beta, bnm, bnv,
        xh, Wt1h, Wt2h, lw1t, lw2t, A1f, B1f);

    const int NT = (NN + 63) / 64;  // 782 tiles
    // layer 0: xh -> hb0
    k_layer<<<NT, 256, 0, stream>>>(xh, hb0, Wt1h, Wt2h, A1f, B1f, b2,
                                    rowstart, deg, csr, NN);
    // layer 1: hb0 -> hb1
    k_layer<<<NT, 256, 0, stream>>>(hb0, hb1, Wt1h + HH * HH, Wt2h + HH * HH,
                                    A1f + HH, B1f + HH, b2 + HH, rowstart, deg, csr, NN);
    // layer 2: hb1 -> hb0
    k_layer<<<NT, 256, 0, stream>>>(hb1, hb0, Wt1h + 2 * HH * HH, Wt2h + 2 * HH * HH,
                                    A1f + 2 * HH, B1f + 2 * HH, b2 + 2 * HH,
                                    rowstart, deg, csr, NN);
    // head
    k_head<<<NT, 256, 0, stream>>>(hb0, lw1t, lw2t, lb1, lb2, out, NN);
}

// Round 2
// 466.175 us; speedup vs baseline: 1.5084x; 1.5084x over previous
//
#include <hip/hip_runtime.h>
#include <hip/hip_bf16.h>
#include <math.h>

// Problem constants (from reference)
#define NN 50000
#define EE 800000
#define HH 128
#define LL 3
#define CC 47

typedef _Float16 half8  __attribute__((ext_vector_type(8)));
typedef _Float16 half2v __attribute__((ext_vector_type(2)));
typedef float    f32x4  __attribute__((ext_vector_type(4)));

__device__ __forceinline__ f32x4 mfma16(half8 a, half8 b, f32x4 c) {
    return __builtin_amdgcn_mfma_f32_16x16x32_f16(a, b, c, 0, 0, 0);
}

// ---------------- CSR build ----------------
__global__ void k_count(const int* __restrict__ ei, int* __restrict__ deg) {
    int e = blockIdx.x * blockDim.x + threadIdx.x;
    if (e < EE) atomicAdd(&deg[ei[EE + e]], 1);
}

__global__ void k_scan(const int* __restrict__ deg, int* __restrict__ rowstart,
                       int* __restrict__ cursor) {
    __shared__ int ps[1024];
    const int t = threadIdx.x;
    const int CH = (NN + 1023) / 1024;  // 49
    const int base = t * CH;
    int s = 0;
    for (int j = 0; j < CH; ++j) {
        int idx = base + j;
        if (idx < NN) s += deg[idx];
    }
    ps[t] = s;
    __syncthreads();
    for (int off = 1; off < 1024; off <<= 1) {
        int v = (t >= off) ? ps[t - off] : 0;
        __syncthreads();
        if (t >= off) ps[t] += v;
        __syncthreads();
    }
    int run = ps[t] - s;  // exclusive prefix
    for (int j = 0; j < CH; ++j) {
        int idx = base + j;
        if (idx < NN) {
            rowstart[idx] = run;
            cursor[idx] = run;
            run += deg[idx];
        }
    }
}

__global__ void k_fill(const int* __restrict__ ei, int* __restrict__ cursor,
                       int* __restrict__ csr) {
    int e = blockIdx.x * blockDim.x + threadIdx.x;
    if (e < EE) {
        int d = ei[EE + e];
        int pos = atomicAdd(&cursor[d], 1);
        csr[pos] = ei[e];  // src
    }
}

// ---------------- prep: fp16 convert, weight transpose, BN fold ----------------
__global__ void k_prep(const float* __restrict__ x, const float* __restrict__ W1,
                       const float* __restrict__ W2, const float* __restrict__ lw1,
                       const float* __restrict__ lw2, const float* __restrict__ b1,
                       const float* __restrict__ gamma, const float* __restrict__ beta,
                       const float* __restrict__ bnm, const float* __restrict__ bnv,
                       _Float16* __restrict__ xh, _Float16* __restrict__ Wt1h,
                       _Float16* __restrict__ Wt2h, _Float16* __restrict__ lw1t,
                       _Float16* __restrict__ lw2t, float* __restrict__ A1f,
                       float* __restrict__ B1f) {
    long i = (long)blockIdx.x * blockDim.x + threadIdx.x;
    const long P0 = (long)NN * HH;        // x convert
    const long P1 = P0 + (long)LL * HH * HH;  // W1 transpose
    const long P2 = P1 + (long)LL * HH * HH;  // W2 transpose
    const long P3 = P2 + HH * HH;             // lw1 transpose
    const long P4 = P3 + 48 * HH;             // lw2 transpose (padded)
    const long P5 = P4 + LL * HH;             // BN fold
    if (i < P0) {
        xh[i] = (_Float16)x[i];
    } else if (i < P1) {
        long j = i - P0;
        int l = (int)(j / (HH * HH));
        int n = (int)((j / HH) % HH);
        int k = (int)(j % HH);
        Wt1h[l * HH * HH + n * HH + k] = (_Float16)W1[l * HH * HH + k * HH + n];
    } else if (i < P2) {
        long j = i - P1;
        int l = (int)(j / (HH * HH));
        int n = (int)((j / HH) % HH);
        int k = (int)(j % HH);
        Wt2h[l * HH * HH + n * HH + k] = (_Float16)W2[l * HH * HH + k * HH + n];
    } else if (i < P3) {
        long j = i - P2;
        int n = (int)(j / HH), k = (int)(j % HH);
        lw1t[n * HH + k] = (_Float16)lw1[k * HH + n];
    } else if (i < P4) {
        long j = i - P3;
        int n = (int)(j / HH), k = (int)(j % HH);
        lw2t[n * HH + k] = (_Float16)((n < CC) ? lw2[k * CC + n] : 0.f);
    } else if (i < P5) {
        long j = i - P4;
        float s = gamma[j] * rsqrtf(bnv[j] + 1e-5f);
        A1f[j] = s;
        B1f[j] = (b1[j] - bnm[j]) * s + beta[j];
    }
}

// ---------------- gather: agg[i] = h[i] + sum_{j in N(i)} h[j], fp16 ----------------
// 16 lanes per node, each lane owns 8 features (16 B). A wave runs 4 nodes'
// edge loops concurrently -> 4x MLP. No LDS, low VGPR -> max occupancy.
__global__ __launch_bounds__(256) void k_gather(
    const _Float16* __restrict__ hin, _Float16* __restrict__ agg,
    const int* __restrict__ rowstart, const int* __restrict__ degs,
    const int* __restrict__ csr, int nn) {
    const int t = blockIdx.x * 256 + threadIdx.x;
    const int node = t >> 4;
    const int fo = (threadIdx.x & 15) * 8;  // feature offset
    if (node >= nn) return;
    const size_t base = (size_t)node * HH + fo;
    half8 hv = *(const half8*)(hin + base);
    float a[8];
#pragma unroll
    for (int j = 0; j < 8; ++j) a[j] = (float)hv[j];
    const int e0 = rowstart[node];
    const int d = degs[node];
#pragma unroll 4
    for (int e = e0; e < e0 + d; ++e) {
        const int s = csr[e];
        half8 v = *(const half8*)(hin + (size_t)s * HH + fo);
#pragma unroll
        for (int j = 0; j < 8; ++j) a[j] += (float)v[j];
    }
    half8 o;
#pragma unroll
    for (int j = 0; j < 8; ++j) o[j] = (_Float16)a[j];
    *(half8*)(agg + base) = o;
}

// ---------------- MLP: GEMM1 + foldedBN + relu + GEMM2 + relu ----------------
// Tile: 64 nodes per block, 256 threads (4 waves). Wave w owns cols 32w..32w+31.
// LDS: A-tile 64x136 fp16 (reused for Z), weights 128x136 fp16 (staged twice).
__global__ __launch_bounds__(256) void k_mlp(
    const _Float16* __restrict__ aggh, _Float16* __restrict__ hout,
    const _Float16* __restrict__ Wt1, const _Float16* __restrict__ Wt2,
    const float* __restrict__ A1, const float* __restrict__ B1,
    const float* __restrict__ b2, int nn) {
    __shared__ _Float16 Ab[64 * 136];
    __shared__ _Float16 Ws[128 * 136];
    const int tid = threadIdx.x;
    const int wave = tid >> 6, lane = tid & 63;
    const int q = lane >> 4, l15 = lane & 15;
    const int tile0 = blockIdx.x * 64;

    // stage Wt1 -> LDS (stride 136, 16B aligned rows)
    {
        int r = tid >> 4;
        const int c = (tid & 15) * 8;
#pragma unroll
        for (int it = 0; it < 8; ++it, r += 16)
            *(half8*)(Ws + r * 136 + c) = *(const half8*)(Wt1 + r * 128 + c);
    }
    // stage A rows from aggh
    {
        int r = tid >> 4;
        const int c = (tid & 15) * 8;
#pragma unroll
        for (int it = 0; it < 4; ++it, r += 16) {
            const int g = tile0 + r;
            half8 v = {0, 0, 0, 0, 0, 0, 0, 0};
            if (g < nn) v = *(const half8*)(aggh + (size_t)g * HH + c);
            *(half8*)(Ab + r * 136 + c) = v;
        }
    }
    __syncthreads();

    // GEMM1: all 64 rows x 32 cols per wave
    f32x4 acc[4][2];
#pragma unroll
    for (int s = 0; s < 4; ++s)
#pragma unroll
        for (int t = 0; t < 2; ++t) acc[s][t] = (f32x4){0.f, 0.f, 0.f, 0.f};
#pragma unroll
    for (int kt = 0; kt < 4; ++kt) {
        const int ko = kt * 32 + q * 8;
        half8 a0 = *(const half8*)(Ab + (0 * 16 + l15) * 136 + ko);
        half8 a1 = *(const half8*)(Ab + (1 * 16 + l15) * 136 + ko);
        half8 a2 = *(const half8*)(Ab + (2 * 16 + l15) * 136 + ko);
        half8 a3 = *(const half8*)(Ab + (3 * 16 + l15) * 136 + ko);
        half8 bb0 = *(const half8*)(Ws + (wave * 32 + 0 * 16 + l15) * 136 + ko);
        half8 bb1 = *(const half8*)(Ws + (wave * 32 + 1 * 16 + l15) * 136 + ko);
        acc[0][0] = mfma16(a0, bb0, acc[0][0]);
        acc[1][0] = mfma16(a1, bb0, acc[1][0]);
        acc[2][0] = mfma16(a2, bb0, acc[2][0]);
        acc[3][0] = mfma16(a3, bb0, acc[3][0]);
        acc[0][1] = mfma16(a0, bb1, acc[0][1]);
        acc[1][1] = mfma16(a1, bb1, acc[1][1]);
        acc[2][1] = mfma16(a2, bb1, acc[2][1]);
        acc[3][1] = mfma16(a3, bb1, acc[3][1]);
    }
    __syncthreads();

    // stage Wt2
    {
        int r = tid >> 4;
        const int c = (tid & 15) * 8;
#pragma unroll
        for (int it = 0; it < 8; ++it, r += 16)
            *(half8*)(Ws + r * 136 + c) = *(const half8*)(Wt2 + r * 128 + c);
    }
    // epilogue1: folded BN + relu -> Z into Ab
#pragma unroll
    for (int t = 0; t < 2; ++t) {
        const int col = wave * 32 + t * 16 + l15;
        const float sc = A1[col], sh = B1[col];
#pragma unroll
        for (int s = 0; s < 4; ++s)
#pragma unroll
            for (int r = 0; r < 4; ++r) {
                const int row = s * 16 + q * 4 + r;
                float v = acc[s][t][r] * sc + sh;
                Ab[row * 136 + col] = (_Float16)fmaxf(v, 0.f);
            }
    }
    __syncthreads();

    // GEMM2
#pragma unroll
    for (int s = 0; s < 4; ++s)
#pragma unroll
        for (int t = 0; t < 2; ++t) acc[s][t] = (f32x4){0.f, 0.f, 0.f, 0.f};
#pragma unroll
    for (int kt = 0; kt < 4; ++kt) {
        const int ko = kt * 32 + q * 8;
        half8 a0 = *(const half8*)(Ab + (0 * 16 + l15) * 136 + ko);
        half8 a1 = *(const half8*)(Ab + (1 * 16 + l15) * 136 + ko);
        half8 a2 = *(const half8*)(Ab + (2 * 16 + l15) * 136 + ko);
        half8 a3 = *(const half8*)(Ab + (3 * 16 + l15) * 136 + ko);
        half8 bb0 = *(const half8*)(Ws + (wave * 32 + 0 * 16 + l15) * 136 + ko);
        half8 bb1 = *(const half8*)(Ws + (wave * 32 + 1 * 16 + l15) * 136 + ko);
        acc[0][0] = mfma16(a0, bb0, acc[0][0]);
        acc[1][0] = mfma16(a1, bb0, acc[1][0]);
        acc[2][0] = mfma16(a2, bb0, acc[2][0]);
        acc[3][0] = mfma16(a3, bb0, acc[3][0]);
        acc[0][1] = mfma16(a0, bb1, acc[0][1]);
        acc[1][1] = mfma16(a1, bb1, acc[1][1]);
        acc[2][1] = mfma16(a2, bb1, acc[2][1]);
        acc[3][1] = mfma16(a3, bb1, acc[3][1]);
    }
    // epilogue2: +b2, relu, store
#pragma unroll
    for (int t = 0; t < 2; ++t) {
        const int col = wave * 32 + t * 16 + l15;
        const float bb = b2[col];
#pragma unroll
        for (int s = 0; s < 4; ++s)
#pragma unroll
            for (int r = 0; r < 4; ++r) {
                const int row = s * 16 + q * 4 + r;
                const int g = tile0 + row;
                if (g < nn) {
                    float v = fmaxf(acc[s][t][r] + bb, 0.f);
                    hout[(size_t)g * HH + col] = (_Float16)v;
                }
            }
    }
}

// ---------------- head: GEMM(lw1)+relu -> GEMM(lw2,47 pad 48) -> log_softmax ----------------
__global__ __launch_bounds__(256) void k_head(const _Float16* __restrict__ hin,
                                              const _Float16* __restrict__ lw1t,
                                              const _Float16* __restrict__ lw2t,
                                              const float* __restrict__ lb1,
                                              const float* __restrict__ lb2,
                                              float* __restrict__ out, int nn) {
    __shared__ _Float16 Ab[64 * 136];
    __shared__ _Float16 Ws[128 * 136];
    const int tid = threadIdx.x;
    const int wave = tid >> 6, lane = tid & 63;
    const int q = lane >> 4, l15 = lane & 15;
    const int tile0 = blockIdx.x * 64;

    // stage A rows (h3)
    {
        int r = tid >> 4;
        const int c = (tid & 15) * 8;
#pragma unroll
        for (int it = 0; it < 4; ++it, r += 16) {
            const int g = tile0 + r;
            half8 v = {0, 0, 0, 0, 0, 0, 0, 0};
            if (g < nn) v = *(const half8*)(hin + (size_t)g * 128 + c);
            *(half8*)(Ab + r * 136 + c) = v;
        }
    }
    // stage lw1t
    {
        int r = tid >> 4;
        const int c = (tid & 15) * 8;
#pragma unroll
        for (int it = 0; it < 8; ++it, r += 16)
            *(half8*)(Ws + r * 136 + c) = *(const half8*)(lw1t + r * 128 + c);
    }
    __syncthreads();

    // GEMM1
    f32x4 acc[4][2];
#pragma unroll
    for (int s = 0; s < 4; ++s)
#pragma unroll
        for (int t = 0; t < 2; ++t) acc[s][t] = (f32x4){0.f, 0.f, 0.f, 0.f};
#pragma unroll
    for (int kt = 0; kt < 4; ++kt) {
        const int ko = kt * 32 + q * 8;
        half8 a0 = *(const half8*)(Ab + (0 * 16 + l15) * 136 + ko);
        half8 a1 = *(const half8*)(Ab + (1 * 16 + l15) * 136 + ko);
        half8 a2 = *(const half8*)(Ab + (2 * 16 + l15) * 136 + ko);
        half8 a3 = *(const half8*)(Ab + (3 * 16 + l15) * 136 + ko);
        half8 bb0 = *(const half8*)(Ws + (wave * 32 + 0 * 16 + l15) * 136 + ko);
        half8 bb1 = *(const half8*)(Ws + (wave * 32 + 1 * 16 + l15) * 136 + ko);
        acc[0][0] = mfma16(a0, bb0, acc[0][0]);
        acc[1][0] = mfma16(a1, bb0, acc[1][0]);
        acc[2][0] = mfma16(a2, bb0, acc[2][0]);
        acc[3][0] = mfma16(a3, bb0, acc[3][0]);
        acc[0][1] = mfma16(a0, bb1, acc[0][1]);
        acc[1][1] = mfma16(a1, bb1, acc[1][1]);
        acc[2][1] = mfma16(a2, bb1, acc[2][1]);
        acc[3][1] = mfma16(a3, bb1, acc[3][1]);
    }
    __syncthreads();

    // stage lw2t (48 rows)
    {
        int r = tid >> 4;
        const int c = (tid & 15) * 8;
#pragma unroll
        for (int it = 0; it < 3; ++it, r += 16)
            *(half8*)(Ws + r * 136 + c) = *(const half8*)(lw2t + r * 128 + c);
    }
    // epilogue1: +lb1, relu -> Ab
#pragma unroll
    for (int t = 0; t < 2; ++t) {
        const int col = wave * 32 + t * 16 + l15;
        const float bb = lb1[col];
#pragma unroll
        for (int s = 0; s < 4; ++s)
#pragma unroll
            for (int r = 0; r < 4; ++r) {
                const int row = s * 16 + q * 4 + r;
                float v = fmaxf(acc[s][t][r] + bb, 0.f);
                Ab[row * 136 + col] = (_Float16)v;
            }
    }
    __syncthreads();

    // GEMM2: 48 cols, waves 0..2 take 16 cols each
    f32x4 acc2[4];
#pragma unroll
    for (int s = 0; s < 4; ++s) acc2[s] = (f32x4){0.f, 0.f, 0.f, 0.f};
    if (wave < 3) {
#pragma unroll
        for (int kt = 0; kt < 4; ++kt) {
            const int ko = kt * 32 + q * 8;
            half8 a0 = *(const half8*)(Ab + (0 * 16 + l15) * 136 + ko);
            half8 a1 = *(const half8*)(Ab + (1 * 16 + l15) * 136 + ko);
            half8 a2 = *(const half8*)(Ab + (2 * 16 + l15) * 136 + ko);
            half8 a3 = *(const half8*)(Ab + (3 * 16 + l15) * 136 + ko);
            half8 bb = *(const half8*)(Ws + (wave * 16 + l15) * 136 + ko);
            acc2[0] = mfma16(a0, bb, acc2[0]);
            acc2[1] = mfma16(a1, bb, acc2[1]);
            acc2[2] = mfma16(a2, bb, acc2[2]);
            acc2[3] = mfma16(a3, bb, acc2[3]);
        }
    }
    __syncthreads();  // all reads of Ab done before aliasing as float buffer

    float* Lb = (float*)Ab;  // 64 x 49 floats = 12.5 KB
    if (wave < 3) {
        const int col = wave * 16 + l15;
        const float bb = (col < CC) ? lb2[col] : 0.f;
#pragma unroll
        for (int s = 0; s < 4; ++s)
#pragma unroll
            for (int r = 0; r < 4; ++r) {
                const int row = s * 16 + q * 4 + r;
                Lb[row * 49 + col] = acc2[s][r] + bb;
            }
    }
    __syncthreads();

    // log_softmax: one thread per row
    if (tid < 64) {
        const int g = tile0 + tid;
        if (g < nn) {
            float m = -1e30f;
            for (int c = 0; c < CC; ++c) m = fmaxf(m, Lb[tid * 49 + c]);
            float ssum = 0.f;
            for (int c = 0; c < CC; ++c) ssum += expf(Lb[tid * 49 + c] - m);
            const float ls = logf(ssum) + m;
            for (int c = 0; c < CC; ++c) out[(size_t)g * CC + c] = Lb[tid * 49 + c] - ls;
        }
    }
}

// ---------------- host ----------------
extern "C" void kernel_launch(void* const* d_in, const int* in_sizes, int n_in,
                              void* d_out, int out_size, void* d_ws, size_t ws_size,
                              hipStream_t stream) {
    const float* x     = (const float*)d_in[0];
    const int*   ei    = (const int*)d_in[1];
    const float* W1    = (const float*)d_in[2];
    const float* b1    = (const float*)d_in[3];
    const float* gamma = (const float*)d_in[4];
    const float* beta  = (const float*)d_in[5];
    const float* bnm   = (const float*)d_in[6];
    const float* bnv   = (const float*)d_in[7];
    const float* W2    = (const float*)d_in[8];
    const float* b2    = (const float*)d_in[9];
    const float* lw1   = (const float*)d_in[10];
    const float* lb1   = (const float*)d_in[11];
    const float* lw2   = (const float*)d_in[12];
    const float* lb2   = (const float*)d_in[13];
    float* out = (float*)d_out;

    char* p = (char*)d_ws;
    auto carve = [&](size_t bytes) -> char* {
        char* r = p;
        p += (bytes + 255) & ~(size_t)255;
        return r;
    };
    int* deg      = (int*)carve((size_t)NN * 4);
    int* rowstart = (int*)carve((size_t)NN * 4);
    int* cursor   = (int*)carve((size_t)NN * 4);
    int* csr      = (int*)carve((size_t)EE * 4);
    _Float16* Wt1h = (_Float16*)carve((size_t)LL * HH * HH * 2);
    _Float16* Wt2h = (_Float16*)carve((size_t)LL * HH * HH * 2);
    _Float16* lw1t = (_Float16*)carve((size_t)HH * HH * 2);
    _Float16* lw2t = (_Float16*)carve((size_t)48 * HH * 2);
    float* A1f = (float*)carve((size_t)LL * HH * 4);
    float* B1f = (float*)carve((size_t)LL * HH * 4);
    _Float16* xh   = (_Float16*)carve((size_t)NN * HH * 2);
    _Float16* hb0  = (_Float16*)carve((size_t)NN * HH * 2);
    _Float16* hb1  = (_Float16*)carve((size_t)NN * HH * 2);
    _Float16* aggb = (_Float16*)carve((size_t)NN * HH * 2);

    // CSR build
    hipMemsetAsync(deg, 0, (size_t)NN * 4, stream);
    k_count<<<(EE + 255) / 256, 256, 0, stream>>>(ei, deg);
    k_scan<<<1, 1024, 0, stream>>>(deg, rowstart, cursor);
    k_fill<<<(EE + 255) / 256, 256, 0, stream>>>(ei, cursor, csr);

    // prep
    const long total = (long)NN * HH + 2L * LL * HH * HH + (long)HH * HH + 48L * HH + (long)LL * HH;
    k_prep<<<(int)((total + 255) / 256), 256, 0, stream>>>(
        x, W1, W2, lw1, lw2, b1, gamma, beta, bnm, bnv,
        xh, Wt1h, Wt2h, lw1t, lw2t, A1f, B1f);

    const int NB_G = (NN * 16 + 255) / 256;  // 3125
    const int NT = (NN + 63) / 64;           // 782 tiles

    // layer 0: xh -> hb0
    k_gather<<<NB_G, 256, 0, stream>>>(xh, aggb, rowstart, deg, csr, NN);
    k_mlp<<<NT, 256, 0, stream>>>(aggb, hb0, Wt1h, Wt2h, A1f, B1f, b2, NN);
    // layer 1: hb0 -> hb1
    k_gather<<<NB_G, 256, 0, stream>>>(hb0, aggb, rowstart, deg, csr, NN);
    k_mlp<<<NT, 256, 0, stream>>>(aggb, hb1, Wt1h + HH * HH, Wt2h + HH * HH,
                                  A1f + HH, B1f + HH, b2 + HH, NN);
    // layer 2: hb1 -> hb0
    k_gather<<<NB_G, 256, 0, stream>>>(hb1, aggb, rowstart, deg, csr, NN);
    k_mlp<<<NT, 256, 0, stream>>>(aggb, hb0, Wt1h + 2 * HH * HH, Wt2h + 2 * HH * HH,
                                  A1f + 2 * HH, B1f + 2 * HH, b2 + 2 * HH, NN);
    // head
    k_head<<<NT, 256, 0, stream>>>(hb0, lw1t, lw2t, lb1, lb2, out, NN);
}

// Round 3
// 358.666 us; speedup vs baseline: 1.9605x; 1.2997x over previous
//
#include <hip/hip_runtime.h>
#include <hip/hip_bf16.h>
#include <math.h>

// Problem constants (from reference)
#define NN 50000
#define EE 800000
#define HH 128
#define LL 3
#define CC 47

#define SCAN_NB ((NN + 255) / 256)  // 196 blocks for the hierarchical scan

typedef _Float16 half8  __attribute__((ext_vector_type(8)));
typedef _Float16 half2v __attribute__((ext_vector_type(2)));
typedef float    f32x4  __attribute__((ext_vector_type(4)));

__device__ __forceinline__ f32x4 mfma16(half8 a, half8 b, f32x4 c) {
    return __builtin_amdgcn_mfma_f32_16x16x32_f16(a, b, c, 0, 0, 0);
}

// ---------------- CSR build ----------------
__global__ void k_count(const int* __restrict__ ei, int* __restrict__ deg) {
    int e = blockIdx.x * blockDim.x + threadIdx.x;
    if (e < EE) atomicAdd(&deg[ei[EE + e]], 1);
}

// hierarchical scan, stage 1: per-256-block sums (coalesced)
__global__ __launch_bounds__(256) void k_blocksum(const int* __restrict__ deg,
                                                  int* __restrict__ blocksum) {
    __shared__ int ws[4];
    const int t = threadIdx.x;
    const int idx = blockIdx.x * 256 + t;
    int v = (idx < NN) ? deg[idx] : 0;
    // wave reduce (64 lanes)
#pragma unroll
    for (int off = 32; off > 0; off >>= 1) v += __shfl_down(v, off, 64);
    if ((t & 63) == 0) ws[t >> 6] = v;
    __syncthreads();
    if (t == 0) blocksum[blockIdx.x] = ws[0] + ws[1] + ws[2] + ws[3];
}

// stage 2: scan the 196 block sums (one block)
__global__ __launch_bounds__(256) void k_scanbs(const int* __restrict__ blocksum,
                                                int* __restrict__ blockoff) {
    __shared__ int ps[256];
    const int t = threadIdx.x;
    int v = (t < SCAN_NB) ? blocksum[t] : 0;
    ps[t] = v;
    __syncthreads();
#pragma unroll
    for (int off = 1; off < 256; off <<= 1) {
        int u = (t >= off) ? ps[t - off] : 0;
        __syncthreads();
        ps[t] += u;
        __syncthreads();
    }
    if (t < SCAN_NB) blockoff[t] = ps[t] - v;  // exclusive
}

// stage 3: per-block exclusive scan + block offset -> rowstart, cursor
__global__ __launch_bounds__(256) void k_apply(const int* __restrict__ deg,
                                               const int* __restrict__ blockoff,
                                               int* __restrict__ rowstart,
                                               int* __restrict__ cursor) {
    __shared__ int ps[256];
    const int t = threadIdx.x;
    const int idx = blockIdx.x * 256 + t;
    int v = (idx < NN) ? deg[idx] : 0;
    ps[t] = v;
    __syncthreads();
#pragma unroll
    for (int off = 1; off < 256; off <<= 1) {
        int u = (t >= off) ? ps[t - off] : 0;
        __syncthreads();
        ps[t] += u;
        __syncthreads();
    }
    if (idx < NN) {
        const int r = blockoff[blockIdx.x] + ps[t] - v;
        rowstart[idx] = r;
        cursor[idx] = r;
    }
}

__global__ void k_fill(const int* __restrict__ ei, int* __restrict__ cursor,
                       int* __restrict__ csr) {
    int e = blockIdx.x * blockDim.x + threadIdx.x;
    if (e < EE) {
        int d = ei[EE + e];
        int pos = atomicAdd(&cursor[d], 1);
        csr[pos] = ei[e];  // src
    }
}

// ---------------- prep: fp16 convert, weight transpose, BN fold ----------------
__global__ void k_prep(const float* __restrict__ x, const float* __restrict__ W1,
                       const float* __restrict__ W2, const float* __restrict__ lw1,
                       const float* __restrict__ lw2, const float* __restrict__ b1,
                       const float* __restrict__ gamma, const float* __restrict__ beta,
                       const float* __restrict__ bnm, const float* __restrict__ bnv,
                       _Float16* __restrict__ xh, _Float16* __restrict__ Wt1h,
                       _Float16* __restrict__ Wt2h, _Float16* __restrict__ lw1t,
                       _Float16* __restrict__ lw2t, float* __restrict__ A1f,
                       float* __restrict__ B1f) {
    long i = (long)blockIdx.x * blockDim.x + threadIdx.x;
    const long P0 = (long)NN * HH;        // x convert
    const long P1 = P0 + (long)LL * HH * HH;  // W1 transpose
    const long P2 = P1 + (long)LL * HH * HH;  // W2 transpose
    const long P3 = P2 + HH * HH;             // lw1 transpose
    const long P4 = P3 + 48 * HH;             // lw2 transpose (padded)
    const long P5 = P4 + LL * HH;             // BN fold
    if (i < P0) {
        xh[i] = (_Float16)x[i];
    } else if (i < P1) {
        long j = i - P0;
        int l = (int)(j / (HH * HH));
        int n = (int)((j / HH) % HH);
        int k = (int)(j % HH);
        Wt1h[l * HH * HH + n * HH + k] = (_Float16)W1[l * HH * HH + k * HH + n];
    } else if (i < P2) {
        long j = i - P1;
        int l = (int)(j / (HH * HH));
        int n = (int)((j / HH) % HH);
        int k = (int)(j % HH);
        Wt2h[l * HH * HH + n * HH + k] = (_Float16)W2[l * HH * HH + k * HH + n];
    } else if (i < P3) {
        long j = i - P2;
        int n = (int)(j / HH), k = (int)(j % HH);
        lw1t[n * HH + k] = (_Float16)lw1[k * HH + n];
    } else if (i < P4) {
        long j = i - P3;
        int n = (int)(j / HH), k = (int)(j % HH);
        lw2t[n * HH + k] = (_Float16)((n < CC) ? lw2[k * CC + n] : 0.f);
    } else if (i < P5) {
        long j = i - P4;
        float s = gamma[j] * rsqrtf(bnv[j] + 1e-5f);
        A1f[j] = s;
        B1f[j] = (b1[j] - bnm[j]) * s + beta[j];
    }
}

// ---------------- gather: agg[i] = h[i] + sum_{j in N(i)} h[j], fp16 ----------------
// 16 lanes per node, each lane owns 8 features (16 B). A wave runs 4 nodes'
// edge loops concurrently -> 4x MLP. No LDS, low VGPR -> max occupancy.
__global__ __launch_bounds__(256) void k_gather(
    const _Float16* __restrict__ hin, _Float16* __restrict__ agg,
    const int* __restrict__ rowstart, const int* __restrict__ degs,
    const int* __restrict__ csr, int nn) {
    const int t = blockIdx.x * 256 + threadIdx.x;
    const int node = t >> 4;
    const int fo = (threadIdx.x & 15) * 8;  // feature offset
    if (node >= nn) return;
    const size_t base = (size_t)node * HH + fo;
    half8 hv = *(const half8*)(hin + base);
    float a[8];
#pragma unroll
    for (int j = 0; j < 8; ++j) a[j] = (float)hv[j];
    const int e0 = rowstart[node];
    const int d = degs[node];
#pragma unroll 4
    for (int e = e0; e < e0 + d; ++e) {
        const int s = csr[e];
        half8 v = *(const half8*)(hin + (size_t)s * HH + fo);
#pragma unroll
        for (int j = 0; j < 8; ++j) a[j] += (float)v[j];
    }
    half8 o;
#pragma unroll
    for (int j = 0; j < 8; ++j) o[j] = (_Float16)a[j];
    *(half8*)(agg + base) = o;
}

// ---------------- MLP: GEMM1 + foldedBN + relu + GEMM2 + relu ----------------
// Tile: 64 nodes per block, 256 threads (4 waves). Wave w owns cols 32w..32w+31.
// LDS: A-tile 64x136 fp16 (reused for Z), weights 128x136 fp16 (staged twice).
__global__ __launch_bounds__(256) void k_mlp(
    const _Float16* __restrict__ aggh, _Float16* __restrict__ hout,
    const _Float16* __restrict__ Wt1, const _Float16* __restrict__ Wt2,
    const float* __restrict__ A1, const float* __restrict__ B1,
    const float* __restrict__ b2, int nn) {
    __shared__ _Float16 Ab[64 * 136];
    __shared__ _Float16 Ws[128 * 136];
    const int tid = threadIdx.x;
    const int wave = tid >> 6, lane = tid & 63;
    const int q = lane >> 4, l15 = lane & 15;
    const int tile0 = blockIdx.x * 64;

    // stage Wt1 -> LDS (stride 136, 16B aligned rows)
    {
        int r = tid >> 4;
        const int c = (tid & 15) * 8;
#pragma unroll
        for (int it = 0; it < 8; ++it, r += 16)
            *(half8*)(Ws + r * 136 + c) = *(const half8*)(Wt1 + r * 128 + c);
    }
    // stage A rows from aggh
    {
        int r = tid >> 4;
        const int c = (tid & 15) * 8;
#pragma unroll
        for (int it = 0; it < 4; ++it, r += 16) {
            const int g = tile0 + r;
            half8 v = {0, 0, 0, 0, 0, 0, 0, 0};
            if (g < nn) v = *(const half8*)(aggh + (size_t)g * HH + c);
            *(half8*)(Ab + r * 136 + c) = v;
        }
    }
    __syncthreads();

    // GEMM1: all 64 rows x 32 cols per wave
    f32x4 acc[4][2];
#pragma unroll
    for (int s = 0; s < 4; ++s)
#pragma unroll
        for (int t = 0; t < 2; ++t) acc[s][t] = (f32x4){0.f, 0.f, 0.f, 0.f};
#pragma unroll
    for (int kt = 0; kt < 4; ++kt) {
        const int ko = kt * 32 + q * 8;
        half8 a0 = *(const half8*)(Ab + (0 * 16 + l15) * 136 + ko);
        half8 a1 = *(const half8*)(Ab + (1 * 16 + l15) * 136 + ko);
        half8 a2 = *(const half8*)(Ab + (2 * 16 + l15) * 136 + ko);
        half8 a3 = *(const half8*)(Ab + (3 * 16 + l15) * 136 + ko);
        half8 bb0 = *(const half8*)(Ws + (wave * 32 + 0 * 16 + l15) * 136 + ko);
        half8 bb1 = *(const half8*)(Ws + (wave * 32 + 1 * 16 + l15) * 136 + ko);
        acc[0][0] = mfma16(a0, bb0, acc[0][0]);
        acc[1][0] = mfma16(a1, bb0, acc[1][0]);
        acc[2][0] = mfma16(a2, bb0, acc[2][0]);
        acc[3][0] = mfma16(a3, bb0, acc[3][0]);
        acc[0][1] = mfma16(a0, bb1, acc[0][1]);
        acc[1][1] = mfma16(a1, bb1, acc[1][1]);
        acc[2][1] = mfma16(a2, bb1, acc[2][1]);
        acc[3][1] = mfma16(a3, bb1, acc[3][1]);
    }
    __syncthreads();

    // stage Wt2
    {
        int r = tid >> 4;
        const int c = (tid & 15) * 8;
#pragma unroll
        for (int it = 0; it < 8; ++it, r += 16)
            *(half8*)(Ws + r * 136 + c) = *(const half8*)(Wt2 + r * 128 + c);
    }
    // epilogue1: folded BN + relu -> Z into Ab
#pragma unroll
    for (int t = 0; t < 2; ++t) {
        const int col = wave * 32 + t * 16 + l15;
        const float sc = A1[col], sh = B1[col];
#pragma unroll
        for (int s = 0; s < 4; ++s)
#pragma unroll
            for (int r = 0; r < 4; ++r) {
                const int row = s * 16 + q * 4 + r;
                float v = acc[s][t][r] * sc + sh;
                Ab[row * 136 + col] = (_Float16)fmaxf(v, 0.f);
            }
    }
    __syncthreads();

    // GEMM2
#pragma unroll
    for (int s = 0; s < 4; ++s)
#pragma unroll
        for (int t = 0; t < 2; ++t) acc[s][t] = (f32x4){0.f, 0.f, 0.f, 0.f};
#pragma unroll
    for (int kt = 0; kt < 4; ++kt) {
        const int ko = kt * 32 + q * 8;
        half8 a0 = *(const half8*)(Ab + (0 * 16 + l15) * 136 + ko);
        half8 a1 = *(const half8*)(Ab + (1 * 16 + l15) * 136 + ko);
        half8 a2 = *(const half8*)(Ab + (2 * 16 + l15) * 136 + ko);
        half8 a3 = *(const half8*)(Ab + (3 * 16 + l15) * 136 + ko);
        half8 bb0 = *(const half8*)(Ws + (wave * 32 + 0 * 16 + l15) * 136 + ko);
        half8 bb1 = *(const half8*)(Ws + (wave * 32 + 1 * 16 + l15) * 136 + ko);
        acc[0][0] = mfma16(a0, bb0, acc[0][0]);
        acc[1][0] = mfma16(a1, bb0, acc[1][0]);
        acc[2][0] = mfma16(a2, bb0, acc[2][0]);
        acc[3][0] = mfma16(a3, bb0, acc[3][0]);
        acc[0][1] = mfma16(a0, bb1, acc[0][1]);
        acc[1][1] = mfma16(a1, bb1, acc[1][1]);
        acc[2][1] = mfma16(a2, bb1, acc[2][1]);
        acc[3][1] = mfma16(a3, bb1, acc[3][1]);
    }
    // epilogue2: +b2, relu, store
#pragma unroll
    for (int t = 0; t < 2; ++t) {
        const int col = wave * 32 + t * 16 + l15;
        const float bb = b2[col];
#pragma unroll
        for (int s = 0; s < 4; ++s)
#pragma unroll
            for (int r = 0; r < 4; ++r) {
                const int row = s * 16 + q * 4 + r;
                const int g = tile0 + row;
                if (g < nn) {
                    float v = fmaxf(acc[s][t][r] + bb, 0.f);
                    hout[(size_t)g * HH + col] = (_Float16)v;
                }
            }
    }
}

// ---------------- head: GEMM(lw1)+relu -> GEMM(lw2,47 pad 48) -> log_softmax ----------------
__global__ __launch_bounds__(256) void k_head(const _Float16* __restrict__ hin,
                                              const _Float16* __restrict__ lw1t,
                                              const _Float16* __restrict__ lw2t,
                                              const float* __restrict__ lb1,
                                              const float* __restrict__ lb2,
                                              float* __restrict__ out, int nn) {
    __shared__ _Float16 Ab[64 * 136];
    __shared__ _Float16 Ws[128 * 136];
    const int tid = threadIdx.x;
    const int wave = tid >> 6, lane = tid & 63;
    const int q = lane >> 4, l15 = lane & 15;
    const int tile0 = blockIdx.x * 64;

    // stage A rows (h3)
    {
        int r = tid >> 4;
        const int c = (tid & 15) * 8;
#pragma unroll
        for (int it = 0; it < 4; ++it, r += 16) {
            const int g = tile0 + r;
            half8 v = {0, 0, 0, 0, 0, 0, 0, 0};
            if (g < nn) v = *(const half8*)(hin + (size_t)g * 128 + c);
            *(half8*)(Ab + r * 136 + c) = v;
        }
    }
    // stage lw1t
    {
        int r = tid >> 4;
        const int c = (tid & 15) * 8;
#pragma unroll
        for (int it = 0; it < 8; ++it, r += 16)
            *(half8*)(Ws + r * 136 + c) = *(const half8*)(lw1t + r * 128 + c);
    }
    __syncthreads();

    // GEMM1
    f32x4 acc[4][2];
#pragma unroll
    for (int s = 0; s < 4; ++s)
#pragma unroll
        for (int t = 0; t < 2; ++t) acc[s][t] = (f32x4){0.f, 0.f, 0.f, 0.f};
#pragma unroll
    for (int kt = 0; kt < 4; ++kt) {
        const int ko = kt * 32 + q * 8;
        half8 a0 = *(const half8*)(Ab + (0 * 16 + l15) * 136 + ko);
        half8 a1 = *(const half8*)(Ab + (1 * 16 + l15) * 136 + ko);
        half8 a2 = *(const half8*)(Ab + (2 * 16 + l15) * 136 + ko);
        half8 a3 = *(const half8*)(Ab + (3 * 16 + l15) * 136 + ko);
        half8 bb0 = *(const half8*)(Ws + (wave * 32 + 0 * 16 + l15) * 136 + ko);
        half8 bb1 = *(const half8*)(Ws + (wave * 32 + 1 * 16 + l15) * 136 + ko);
        acc[0][0] = mfma16(a0, bb0, acc[0][0]);
        acc[1][0] = mfma16(a1, bb0, acc[1][0]);
        acc[2][0] = mfma16(a2, bb0, acc[2][0]);
        acc[3][0] = mfma16(a3, bb0, acc[3][0]);
        acc[0][1] = mfma16(a0, bb1, acc[0][1]);
        acc[1][1] = mfma16(a1, bb1, acc[1][1]);
        acc[2][1] = mfma16(a2, bb1, acc[2][1]);
        acc[3][1] = mfma16(a3, bb1, acc[3][1]);
    }
    __syncthreads();

    // stage lw2t (48 rows)
    {
        int r = tid >> 4;
        const int c = (tid & 15) * 8;
#pragma unroll
        for (int it = 0; it < 3; ++it, r += 16)
            *(half8*)(Ws + r * 136 + c) = *(const half8*)(lw2t + r * 128 + c);
    }
    // epilogue1: +lb1, relu -> Ab
#pragma unroll
    for (int t = 0; t < 2; ++t) {
        const int col = wave * 32 + t * 16 + l15;
        const float bb = lb1[col];
#pragma unroll
        for (int s = 0; s < 4; ++s)
#pragma unroll
            for (int r = 0; r < 4; ++r) {
                const int row = s * 16 + q * 4 + r;
                float v = fmaxf(acc[s][t][r] + bb, 0.f);
                Ab[row * 136 + col] = (_Float16)v;
            }
    }
    __syncthreads();

    // GEMM2: 48 cols, waves 0..2 take 16 cols each
    f32x4 acc2[4];
#pragma unroll
    for (int s = 0; s < 4; ++s) acc2[s] = (f32x4){0.f, 0.f, 0.f, 0.f};
    if (wave < 3) {
#pragma unroll
        for (int kt = 0; kt < 4; ++kt) {
            const int ko = kt * 32 + q * 8;
            half8 a0 = *(const half8*)(Ab + (0 * 16 + l15) * 136 + ko);
            half8 a1 = *(const half8*)(Ab + (1 * 16 + l15) * 136 + ko);
            half8 a2 = *(const half8*)(Ab + (2 * 16 + l15) * 136 + ko);
            half8 a3 = *(const half8*)(Ab + (3 * 16 + l15) * 136 + ko);
            half8 bb = *(const half8*)(Ws + (wave * 16 + l15) * 136 + ko);
            acc2[0] = mfma16(a0, bb, acc2[0]);
            acc2[1] = mfma16(a1, bb, acc2[1]);
            acc2[2] = mfma16(a2, bb, acc2[2]);
            acc2[3] = mfma16(a3, bb, acc2[3]);
        }
    }
    __syncthreads();  // all reads of Ab done before aliasing as float buffer

    float* Lb = (float*)Ab;  // 64 x 49 floats = 12.5 KB
    if (wave < 3) {
        const int col = wave * 16 + l15;
        const float bb = (col < CC) ? lb2[col] : 0.f;
#pragma unroll
        for (int s = 0; s < 4; ++s)
#pragma unroll
            for (int r = 0; r < 4; ++r) {
                const int row = s * 16 + q * 4 + r;
                Lb[row * 49 + col] = acc2[s][r] + bb;
            }
    }
    __syncthreads();

    // log_softmax: one thread per row
    if (tid < 64) {
        const int g = tile0 + tid;
        if (g < nn) {
            float m = -1e30f;
            for (int c = 0; c < CC; ++c) m = fmaxf(m, Lb[tid * 49 + c]);
            float ssum = 0.f;
            for (int c = 0; c < CC; ++c) ssum += expf(Lb[tid * 49 + c] - m);
            const float ls = logf(ssum) + m;
            for (int c = 0; c < CC; ++c) out[(size_t)g * CC + c] = Lb[tid * 49 + c] - ls;
        }
    }
}

// ---------------- host ----------------
extern "C" void kernel_launch(void* const* d_in, const int* in_sizes, int n_in,
                              void* d_out, int out_size, void* d_ws, size_t ws_size,
                              hipStream_t stream) {
    const float* x     = (const float*)d_in[0];
    const int*   ei    = (const int*)d_in[1];
    const float* W1    = (const float*)d_in[2];
    const float* b1    = (const float*)d_in[3];
    const float* gamma = (const float*)d_in[4];
    const float* beta  = (const float*)d_in[5];
    const float* bnm   = (const float*)d_in[6];
    const float* bnv   = (const float*)d_in[7];
    const float* W2    = (const float*)d_in[8];
    const float* b2    = (const float*)d_in[9];
    const float* lw1   = (const float*)d_in[10];
    const float* lb1   = (const float*)d_in[11];
    const float* lw2   = (const float*)d_in[12];
    const float* lb2   = (const float*)d_in[13];
    float* out = (float*)d_out;

    char* p = (char*)d_ws;
    auto carve = [&](size_t bytes) -> char* {
        char* r = p;
        p += (bytes + 255) & ~(size_t)255;
        return r;
    };
    int* deg      = (int*)carve((size_t)NN * 4);
    int* rowstart = (int*)carve((size_t)NN * 4);
    int* cursor   = (int*)carve((size_t)NN * 4);
    int* csr      = (int*)carve((size_t)EE * 4);
    int* blocksum = (int*)carve((size_t)SCAN_NB * 4);
    int* blockoff = (int*)carve((size_t)SCAN_NB * 4);
    _Float16* Wt1h = (_Float16*)carve((size_t)LL * HH * HH * 2);
    _Float16* Wt2h = (_Float16*)carve((size_t)LL * HH * HH * 2);
    _Float16* lw1t = (_Float16*)carve((size_t)HH * HH * 2);
    _Float16* lw2t = (_Float16*)carve((size_t)48 * HH * 2);
    float* A1f = (float*)carve((size_t)LL * HH * 4);
    float* B1f = (float*)carve((size_t)LL * HH * 4);
    _Float16* xh   = (_Float16*)carve((size_t)NN * HH * 2);
    _Float16* hb0  = (_Float16*)carve((size_t)NN * HH * 2);
    _Float16* hb1  = (_Float16*)carve((size_t)NN * HH * 2);
    _Float16* aggb = (_Float16*)carve((size_t)NN * HH * 2);

    // CSR build
    hipMemsetAsync(deg, 0, (size_t)NN * 4, stream);
    k_count<<<(EE + 255) / 256, 256, 0, stream>>>(ei, deg);
    k_blocksum<<<SCAN_NB, 256, 0, stream>>>(deg, blocksum);
    k_scanbs<<<1, 256, 0, stream>>>(blocksum, blockoff);
    k_apply<<<SCAN_NB, 256, 0, stream>>>(deg, blockoff, rowstart, cursor);
    k_fill<<<(EE + 255) / 256, 256, 0, stream>>>(ei, cursor, csr);

    // prep
    const long total = (long)NN * HH + 2L * LL * HH * HH + (long)HH * HH + 48L * HH + (long)LL * HH;
    k_prep<<<(int)((total + 255) / 256), 256, 0, stream>>>(
        x, W1, W2, lw1, lw2, b1, gamma, beta, bnm, bnv,
        xh, Wt1h, Wt2h, lw1t, lw2t, A1f, B1f);

    const int NB_G = (NN * 16 + 255) / 256;  // 3125
    const int NT = (NN + 63) / 64;           // 782 tiles

    // layer 0: xh -> hb0
    k_gather<<<NB_G, 256, 0, stream>>>(xh, aggb, rowstart, deg, csr, NN);
    k_mlp<<<NT, 256, 0, stream>>>(aggb, hb0, Wt1h, Wt2h, A1f, B1f, b2, NN);
    // layer 1: hb0 -> hb1
    k_gather<<<NB_G, 256, 0, stream>>>(hb0, aggb, rowstart, deg, csr, NN);
    k_mlp<<<NT, 256, 0, stream>>>(aggb, hb1, Wt1h + HH * HH, Wt2h + HH * HH,
                                  A1f + HH, B1f + HH, b2 + HH, NN);
    // layer 2: hb1 -> hb0
    k_gather<<<NB_G, 256, 0, stream>>>(hb1, aggb, rowstart, deg, csr, NN);
    k_mlp<<<NT, 256, 0, stream>>>(aggb, hb0, Wt1h + 2 * HH * HH, Wt2h + 2 * HH * HH,
                                  A1f + 2 * HH, B1f + 2 * HH, b2 + 2 * HH, NN);
    // head
    k_head<<<NT, 256, 0, stream>>>(hb0, lw1t, lw2t, lb1, lb2, out, NN);
}

// Round 4
// 344.232 us; speedup vs baseline: 2.0427x; 1.0419x over previous
//
#include <hip/hip_runtime.h>
#include <hip/hip_bf16.h>
#include <math.h>

// Problem constants (from reference)
#define NN 50000
#define EE 800000
#define HH 128
#define LL 3
#define CC 47

#define SCAN_NB ((NN + 255) / 256)  // 196 blocks for the hierarchical scan

typedef _Float16 half8  __attribute__((ext_vector_type(8)));
typedef _Float16 half2v __attribute__((ext_vector_type(2)));
typedef float    f32x4  __attribute__((ext_vector_type(4)));

__device__ __forceinline__ f32x4 mfma16(half8 a, half8 b, f32x4 c) {
    return __builtin_amdgcn_mfma_f32_16x16x32_f16(a, b, c, 0, 0, 0);
}

// ---------------- CSR build ----------------
__global__ void k_count(const int* __restrict__ ei, int* __restrict__ deg) {
    int e = blockIdx.x * blockDim.x + threadIdx.x;
    if (e < EE) atomicAdd(&deg[ei[EE + e]], 1);
}

// hierarchical scan, stage 1: per-256-block sums (coalesced)
__global__ __launch_bounds__(256) void k_blocksum(const int* __restrict__ deg,
                                                  int* __restrict__ blocksum) {
    __shared__ int ws[4];
    const int t = threadIdx.x;
    const int idx = blockIdx.x * 256 + t;
    int v = (idx < NN) ? deg[idx] : 0;
    // wave reduce (64 lanes)
#pragma unroll
    for (int off = 32; off > 0; off >>= 1) v += __shfl_down(v, off, 64);
    if ((t & 63) == 0) ws[t >> 6] = v;
    __syncthreads();
    if (t == 0) blocksum[blockIdx.x] = ws[0] + ws[1] + ws[2] + ws[3];
}

// stage 2: scan the 196 block sums (one block)
__global__ __launch_bounds__(256) void k_scanbs(const int* __restrict__ blocksum,
                                                int* __restrict__ blockoff) {
    __shared__ int ps[256];
    const int t = threadIdx.x;
    int v = (t < SCAN_NB) ? blocksum[t] : 0;
    ps[t] = v;
    __syncthreads();
#pragma unroll
    for (int off = 1; off < 256; off <<= 1) {
        int u = (t >= off) ? ps[t - off] : 0;
        __syncthreads();
        ps[t] += u;
        __syncthreads();
    }
    if (t < SCAN_NB) blockoff[t] = ps[t] - v;  // exclusive
}

// stage 3: per-block exclusive scan + block offset -> rowstart, cursor
__global__ __launch_bounds__(256) void k_apply(const int* __restrict__ deg,
                                               const int* __restrict__ blockoff,
                                               int* __restrict__ rowstart,
                                               int* __restrict__ cursor) {
    __shared__ int ps[256];
    const int t = threadIdx.x;
    const int idx = blockIdx.x * 256 + t;
    int v = (idx < NN) ? deg[idx] : 0;
    ps[t] = v;
    __syncthreads();
#pragma unroll
    for (int off = 1; off < 256; off <<= 1) {
        int u = (t >= off) ? ps[t - off] : 0;
        __syncthreads();
        ps[t] += u;
        __syncthreads();
    }
    if (idx < NN) {
        const int r = blockoff[blockIdx.x] + ps[t] - v;
        rowstart[idx] = r;
        cursor[idx] = r;
    }
}

// XCD-partitioned fill: block b (round-robins to XCD b&7) handles only dst in
// its 1/8 node range -> each csr cache line is written by ONE XCD's L2, which
// coalesces the ~16 x 4B writes per line (was 16x write amplification to HBM).
__global__ __launch_bounds__(256) void k_fill(const int* __restrict__ ei,
                                              int* __restrict__ cursor,
                                              int* __restrict__ csr) {
    const int part = blockIdx.x & 7;
    const int chunk = blockIdx.x >> 3;
    const int nchunks = gridDim.x >> 3;
    const int lo = part * (NN / 8);  // 6250
    const int hi = (part == 7) ? NN : lo + (NN / 8);
    for (int e = chunk * 256 + threadIdx.x; e < EE; e += nchunks * 256) {
        const int d = ei[EE + e];
        if (d >= lo && d < hi) {
            const int pos = atomicAdd(&cursor[d], 1);
            csr[pos] = ei[e];  // src
        }
    }
}

// ---------------- prep: fp16 convert, weight transpose, BN fold ----------------
__global__ void k_prep(const float* __restrict__ x, const float* __restrict__ W1,
                       const float* __restrict__ W2, const float* __restrict__ lw1,
                       const float* __restrict__ lw2, const float* __restrict__ b1,
                       const float* __restrict__ gamma, const float* __restrict__ beta,
                       const float* __restrict__ bnm, const float* __restrict__ bnv,
                       _Float16* __restrict__ xh, _Float16* __restrict__ Wt1h,
                       _Float16* __restrict__ Wt2h, _Float16* __restrict__ lw1t,
                       _Float16* __restrict__ lw2t, float* __restrict__ A1f,
                       float* __restrict__ B1f) {
    long i = (long)blockIdx.x * blockDim.x + threadIdx.x;
    const long P0 = (long)NN * HH;        // x convert
    const long P1 = P0 + (long)LL * HH * HH;  // W1 transpose
    const long P2 = P1 + (long)LL * HH * HH;  // W2 transpose
    const long P3 = P2 + HH * HH;             // lw1 transpose
    const long P4 = P3 + 48 * HH;             // lw2 transpose (padded)
    const long P5 = P4 + LL * HH;             // BN fold
    if (i < P0) {
        xh[i] = (_Float16)x[i];
    } else if (i < P1) {
        long j = i - P0;
        int l = (int)(j / (HH * HH));
        int n = (int)((j / HH) % HH);
        int k = (int)(j % HH);
        Wt1h[l * HH * HH + n * HH + k] = (_Float16)W1[l * HH * HH + k * HH + n];
    } else if (i < P2) {
        long j = i - P1;
        int l = (int)(j / (HH * HH));
        int n = (int)((j / HH) % HH);
        int k = (int)(j % HH);
        Wt2h[l * HH * HH + n * HH + k] = (_Float16)W2[l * HH * HH + k * HH + n];
    } else if (i < P3) {
        long j = i - P2;
        int n = (int)(j / HH), k = (int)(j % HH);
        lw1t[n * HH + k] = (_Float16)lw1[k * HH + n];
    } else if (i < P4) {
        long j = i - P3;
        int n = (int)(j / HH), k = (int)(j % HH);
        lw2t[n * HH + k] = (_Float16)((n < CC) ? lw2[k * CC + n] : 0.f);
    } else if (i < P5) {
        long j = i - P4;
        float s = gamma[j] * rsqrtf(bnv[j] + 1e-5f);
        A1f[j] = s;
        B1f[j] = (b1[j] - bnm[j]) * s + beta[j];
    }
}

// ---------------- gather: agg[i] = h[i] + sum_{j in N(i)} h[j], fp16 ----------------
// 16 lanes per node, each lane owns 8 features (16 B). A wave runs 4 nodes'
// edge loops concurrently -> 4x MLP. No LDS, low VGPR -> max occupancy.
__global__ __launch_bounds__(256) void k_gather(
    const _Float16* __restrict__ hin, _Float16* __restrict__ agg,
    const int* __restrict__ rowstart, const int* __restrict__ degs,
    const int* __restrict__ csr, int nn) {
    const int t = blockIdx.x * 256 + threadIdx.x;
    const int node = t >> 4;
    const int fo = (threadIdx.x & 15) * 8;  // feature offset
    if (node >= nn) return;
    const size_t base = (size_t)node * HH + fo;
    half8 hv = *(const half8*)(hin + base);
    float a[8];
#pragma unroll
    for (int j = 0; j < 8; ++j) a[j] = (float)hv[j];
    const int e0 = rowstart[node];
    const int d = degs[node];
#pragma unroll 4
    for (int e = e0; e < e0 + d; ++e) {
        const int s = csr[e];
        half8 v = *(const half8*)(hin + (size_t)s * HH + fo);
#pragma unroll
        for (int j = 0; j < 8; ++j) a[j] += (float)v[j];
    }
    half8 o;
#pragma unroll
    for (int j = 0; j < 8; ++j) o[j] = (_Float16)a[j];
    *(half8*)(agg + base) = o;
}

// ---------------- MLP: GEMM1 + foldedBN + relu + GEMM2 + relu ----------------
// Tile: 64 nodes per block, 256 threads (4 waves). Wave w owns cols 32w..32w+31.
// LDS: A-tile 64x136 fp16 (reused for Z), weights 128x136 fp16 (staged twice).
__global__ __launch_bounds__(256) void k_mlp(
    const _Float16* __restrict__ aggh, _Float16* __restrict__ hout,
    const _Float16* __restrict__ Wt1, const _Float16* __restrict__ Wt2,
    const float* __restrict__ A1, const float* __restrict__ B1,
    const float* __restrict__ b2, int nn) {
    __shared__ _Float16 Ab[64 * 136];
    __shared__ _Float16 Ws[128 * 136];
    const int tid = threadIdx.x;
    const int wave = tid >> 6, lane = tid & 63;
    const int q = lane >> 4, l15 = lane & 15;
    const int tile0 = blockIdx.x * 64;

    // stage Wt1 -> LDS (stride 136, 16B aligned rows)
    {
        int r = tid >> 4;
        const int c = (tid & 15) * 8;
#pragma unroll
        for (int it = 0; it < 8; ++it, r += 16)
            *(half8*)(Ws + r * 136 + c) = *(const half8*)(Wt1 + r * 128 + c);
    }
    // stage A rows from aggh
    {
        int r = tid >> 4;
        const int c = (tid & 15) * 8;
#pragma unroll
        for (int it = 0; it < 4; ++it, r += 16) {
            const int g = tile0 + r;
            half8 v = {0, 0, 0, 0, 0, 0, 0, 0};
            if (g < nn) v = *(const half8*)(aggh + (size_t)g * HH + c);
            *(half8*)(Ab + r * 136 + c) = v;
        }
    }
    __syncthreads();

    // GEMM1: all 64 rows x 32 cols per wave
    f32x4 acc[4][2];
#pragma unroll
    for (int s = 0; s < 4; ++s)
#pragma unroll
        for (int t = 0; t < 2; ++t) acc[s][t] = (f32x4){0.f, 0.f, 0.f, 0.f};
#pragma unroll
    for (int kt = 0; kt < 4; ++kt) {
        const int ko = kt * 32 + q * 8;
        half8 a0 = *(const half8*)(Ab + (0 * 16 + l15) * 136 + ko);
        half8 a1 = *(const half8*)(Ab + (1 * 16 + l15) * 136 + ko);
        half8 a2 = *(const half8*)(Ab + (2 * 16 + l15) * 136 + ko);
        half8 a3 = *(const half8*)(Ab + (3 * 16 + l15) * 136 + ko);
        half8 bb0 = *(const half8*)(Ws + (wave * 32 + 0 * 16 + l15) * 136 + ko);
        half8 bb1 = *(const half8*)(Ws + (wave * 32 + 1 * 16 + l15) * 136 + ko);
        acc[0][0] = mfma16(a0, bb0, acc[0][0]);
        acc[1][0] = mfma16(a1, bb0, acc[1][0]);
        acc[2][0] = mfma16(a2, bb0, acc[2][0]);
        acc[3][0] = mfma16(a3, bb0, acc[3][0]);
        acc[0][1] = mfma16(a0, bb1, acc[0][1]);
        acc[1][1] = mfma16(a1, bb1, acc[1][1]);
        acc[2][1] = mfma16(a2, bb1, acc[2][1]);
        acc[3][1] = mfma16(a3, bb1, acc[3][1]);
    }
    __syncthreads();

    // stage Wt2
    {
        int r = tid >> 4;
        const int c = (tid & 15) * 8;
#pragma unroll
        for (int it = 0; it < 8; ++it, r += 16)
            *(half8*)(Ws + r * 136 + c) = *(const half8*)(Wt2 + r * 128 + c);
    }
    // epilogue1: folded BN + relu -> Z into Ab
#pragma unroll
    for (int t = 0; t < 2; ++t) {
        const int col = wave * 32 + t * 16 + l15;
        const float sc = A1[col], sh = B1[col];
#pragma unroll
        for (int s = 0; s < 4; ++s)
#pragma unroll
            for (int r = 0; r < 4; ++r) {
                const int row = s * 16 + q * 4 + r;
                float v = acc[s][t][r] * sc + sh;
                Ab[row * 136 + col] = (_Float16)fmaxf(v, 0.f);
            }
    }
    __syncthreads();

    // GEMM2
#pragma unroll
    for (int s = 0; s < 4; ++s)
#pragma unroll
        for (int t = 0; t < 2; ++t) acc[s][t] = (f32x4){0.f, 0.f, 0.f, 0.f};
#pragma unroll
    for (int kt = 0; kt < 4; ++kt) {
        const int ko = kt * 32 + q * 8;
        half8 a0 = *(const half8*)(Ab + (0 * 16 + l15) * 136 + ko);
        half8 a1 = *(const half8*)(Ab + (1 * 16 + l15) * 136 + ko);
        half8 a2 = *(const half8*)(Ab + (2 * 16 + l15) * 136 + ko);
        half8 a3 = *(const half8*)(Ab + (3 * 16 + l15) * 136 + ko);
        half8 bb0 = *(const half8*)(Ws + (wave * 32 + 0 * 16 + l15) * 136 + ko);
        half8 bb1 = *(const half8*)(Ws + (wave * 32 + 1 * 16 + l15) * 136 + ko);
        acc[0][0] = mfma16(a0, bb0, acc[0][0]);
        acc[1][0] = mfma16(a1, bb0, acc[1][0]);
        acc[2][0] = mfma16(a2, bb0, acc[2][0]);
        acc[3][0] = mfma16(a3, bb0, acc[3][0]);
        acc[0][1] = mfma16(a0, bb1, acc[0][1]);
        acc[1][1] = mfma16(a1, bb1, acc[1][1]);
        acc[2][1] = mfma16(a2, bb1, acc[2][1]);
        acc[3][1] = mfma16(a3, bb1, acc[3][1]);
    }
    // epilogue2: +b2, relu, store
#pragma unroll
    for (int t = 0; t < 2; ++t) {
        const int col = wave * 32 + t * 16 + l15;
        const float bb = b2[col];
#pragma unroll
        for (int s = 0; s < 4; ++s)
#pragma unroll
            for (int r = 0; r < 4; ++r) {
                const int row = s * 16 + q * 4 + r;
                const int g = tile0 + row;
                if (g < nn) {
                    float v = fmaxf(acc[s][t][r] + bb, 0.f);
                    hout[(size_t)g * HH + col] = (_Float16)v;
                }
            }
    }
}

// ---------------- head: GEMM(lw1)+relu -> GEMM(lw2,47 pad 48) -> log_softmax ----------------
__global__ __launch_bounds__(256) void k_head(const _Float16* __restrict__ hin,
                                              const _Float16* __restrict__ lw1t,
                                              const _Float16* __restrict__ lw2t,
                                              const float* __restrict__ lb1,
                                              const float* __restrict__ lb2,
                                              float* __restrict__ out, int nn) {
    __shared__ _Float16 Ab[64 * 136];
    __shared__ _Float16 Ws[128 * 136];
    const int tid = threadIdx.x;
    const int wave = tid >> 6, lane = tid & 63;
    const int q = lane >> 4, l15 = lane & 15;
    const int tile0 = blockIdx.x * 64;

    // stage A rows (h3)
    {
        int r = tid >> 4;
        const int c = (tid & 15) * 8;
#pragma unroll
        for (int it = 0; it < 4; ++it, r += 16) {
            const int g = tile0 + r;
            half8 v = {0, 0, 0, 0, 0, 0, 0, 0};
            if (g < nn) v = *(const half8*)(hin + (size_t)g * 128 + c);
            *(half8*)(Ab + r * 136 + c) = v;
        }
    }
    // stage lw1t
    {
        int r = tid >> 4;
        const int c = (tid & 15) * 8;
#pragma unroll
        for (int it = 0; it < 8; ++it, r += 16)
            *(half8*)(Ws + r * 136 + c) = *(const half8*)(lw1t + r * 128 + c);
    }
    __syncthreads();

    // GEMM1
    f32x4 acc[4][2];
#pragma unroll
    for (int s = 0; s < 4; ++s)
#pragma unroll
        for (int t = 0; t < 2; ++t) acc[s][t] = (f32x4){0.f, 0.f, 0.f, 0.f};
#pragma unroll
    for (int kt = 0; kt < 4; ++kt) {
        const int ko = kt * 32 + q * 8;
        half8 a0 = *(const half8*)(Ab + (0 * 16 + l15) * 136 + ko);
        half8 a1 = *(const half8*)(Ab + (1 * 16 + l15) * 136 + ko);
        half8 a2 = *(const half8*)(Ab + (2 * 16 + l15) * 136 + ko);
        half8 a3 = *(const half8*)(Ab + (3 * 16 + l15) * 136 + ko);
        half8 bb0 = *(const half8*)(Ws + (wave * 32 + 0 * 16 + l15) * 136 + ko);
        half8 bb1 = *(const half8*)(Ws + (wave * 32 + 1 * 16 + l15) * 136 + ko);
        acc[0][0] = mfma16(a0, bb0, acc[0][0]);
        acc[1][0] = mfma16(a1, bb0, acc[1][0]);
        acc[2][0] = mfma16(a2, bb0, acc[2][0]);
        acc[3][0] = mfma16(a3, bb0, acc[3][0]);
        acc[0][1] = mfma16(a0, bb1, acc[0][1]);
        acc[1][1] = mfma16(a1, bb1, acc[1][1]);
        acc[2][1] = mfma16(a2, bb1, acc[2][1]);
        acc[3][1] = mfma16(a3, bb1, acc[3][1]);
    }
    __syncthreads();

    // stage lw2t (48 rows)
    {
        int r = tid >> 4;
        const int c = (tid & 15) * 8;
#pragma unroll
        for (int it = 0; it < 3; ++it, r += 16)
            *(half8*)(Ws + r * 136 + c) = *(const half8*)(lw2t + r * 128 + c);
    }
    // epilogue1: +lb1, relu -> Ab
#pragma unroll
    for (int t = 0; t < 2; ++t) {
        const int col = wave * 32 + t * 16 + l15;
        const float bb = lb1[col];
#pragma unroll
        for (int s = 0; s < 4; ++s)
#pragma unroll
            for (int r = 0; r < 4; ++r) {
                const int row = s * 16 + q * 4 + r;
                float v = fmaxf(acc[s][t][r] + bb, 0.f);
                Ab[row * 136 + col] = (_Float16)v;
            }
    }
    __syncthreads();

    // GEMM2: 48 cols, waves 0..2 take 16 cols each
    f32x4 acc2[4];
#pragma unroll
    for (int s = 0; s < 4; ++s) acc2[s] = (f32x4){0.f, 0.f, 0.f, 0.f};
    if (wave < 3) {
#pragma unroll
        for (int kt = 0; kt < 4; ++kt) {
            const int ko = kt * 32 + q * 8;
            half8 a0 = *(const half8*)(Ab + (0 * 16 + l15) * 136 + ko);
            half8 a1 = *(const half8*)(Ab + (1 * 16 + l15) * 136 + ko);
            half8 a2 = *(const half8*)(Ab + (2 * 16 + l15) * 136 + ko);
            half8 a3 = *(const half8*)(Ab + (3 * 16 + l15) * 136 + ko);
            half8 bb = *(const half8*)(Ws + (wave * 16 + l15) * 136 + ko);
            acc2[0] = mfma16(a0, bb, acc2[0]);
            acc2[1] = mfma16(a1, bb, acc2[1]);
            acc2[2] = mfma16(a2, bb, acc2[2]);
            acc2[3] = mfma16(a3, bb, acc2[3]);
        }
    }
    __syncthreads();  // all reads of Ab done before aliasing as float buffer

    float* Lb = (float*)Ab;  // 64 x 49 floats = 12.5 KB
    if (wave < 3) {
        const int col = wave * 16 + l15;
        const float bb = (col < CC) ? lb2[col] : 0.f;
#pragma unroll
        for (int s = 0; s < 4; ++s)
#pragma unroll
            for (int r = 0; r < 4; ++r) {
                const int row = s * 16 + q * 4 + r;
                Lb[row * 49 + col] = acc2[s][r] + bb;
            }
    }
    __syncthreads();

    // log_softmax: one thread per row
    if (tid < 64) {
        const int g = tile0 + tid;
        if (g < nn) {
            float m = -1e30f;
            for (int c = 0; c < CC; ++c) m = fmaxf(m, Lb[tid * 49 + c]);
            float ssum = 0.f;
            for (int c = 0; c < CC; ++c) ssum += expf(Lb[tid * 49 + c] - m);
            const float ls = logf(ssum) + m;
            for (int c = 0; c < CC; ++c) out[(size_t)g * CC + c] = Lb[tid * 49 + c] - ls;
        }
    }
}

// ---------------- host ----------------
extern "C" void kernel_launch(void* const* d_in, const int* in_sizes, int n_in,
                              void* d_out, int out_size, void* d_ws, size_t ws_size,
                              hipStream_t stream) {
    const float* x     = (const float*)d_in[0];
    const int*   ei    = (const int*)d_in[1];
    const float* W1    = (const float*)d_in[2];
    const float* b1    = (const float*)d_in[3];
    const float* gamma = (const float*)d_in[4];
    const float* beta  = (const float*)d_in[5];
    const float* bnm   = (const float*)d_in[6];
    const float* bnv   = (const float*)d_in[7];
    const float* W2    = (const float*)d_in[8];
    const float* b2    = (const float*)d_in[9];
    const float* lw1   = (const float*)d_in[10];
    const float* lb1   = (const float*)d_in[11];
    const float* lw2   = (const float*)d_in[12];
    const float* lb2   = (const float*)d_in[13];
    float* out = (float*)d_out;

    char* p = (char*)d_ws;
    auto carve = [&](size_t bytes) -> char* {
        char* r = p;
        p += (bytes + 255) & ~(size_t)255;
        return r;
    };
    int* deg      = (int*)carve((size_t)NN * 4);
    int* rowstart = (int*)carve((size_t)NN * 4);
    int* cursor   = (int*)carve((size_t)NN * 4);
    int* csr      = (int*)carve((size_t)EE * 4);
    int* blocksum = (int*)carve((size_t)SCAN_NB * 4);
    int* blockoff = (int*)carve((size_t)SCAN_NB * 4);
    _Float16* Wt1h = (_Float16*)carve((size_t)LL * HH * HH * 2);
    _Float16* Wt2h = (_Float16*)carve((size_t)LL * HH * HH * 2);
    _Float16* lw1t = (_Float16*)carve((size_t)HH * HH * 2);
    _Float16* lw2t = (_Float16*)carve((size_t)48 * HH * 2);
    float* A1f = (float*)carve((size_t)LL * HH * 4);
    float* B1f = (float*)carve((size_t)LL * HH * 4);
    _Float16* xh   = (_Float16*)carve((size_t)NN * HH * 2);
    _Float16* hb0  = (_Float16*)carve((size_t)NN * HH * 2);
    _Float16* hb1  = (_Float16*)carve((size_t)NN * HH * 2);
    _Float16* aggb = (_Float16*)carve((size_t)NN * HH * 2);

    // CSR build
    hipMemsetAsync(deg, 0, (size_t)NN * 4, stream);
    k_count<<<(EE + 255) / 256, 256, 0, stream>>>(ei, deg);
    k_blocksum<<<SCAN_NB, 256, 0, stream>>>(deg, blocksum);
    k_scanbs<<<1, 256, 0, stream>>>(blocksum, blockoff);
    k_apply<<<SCAN_NB, 256, 0, stream>>>(deg, blockoff, rowstart, cursor);
    k_fill<<<2048, 256, 0, stream>>>(ei, cursor, csr);

    // prep
    const long total = (long)NN * HH + 2L * LL * HH * HH + (long)HH * HH + 48L * HH + (long)LL * HH;
    k_prep<<<(int)((total + 255) / 256), 256, 0, stream>>>(
        x, W1, W2, lw1, lw2, b1, gamma, beta, bnm, bnv,
        xh, Wt1h, Wt2h, lw1t, lw2t, A1f, B1f);

    const int NB_G = (NN * 16 + 255) / 256;  // 3125
    const int NT = (NN + 63) / 64;           // 782 tiles

    // layer 0: xh -> hb0
    k_gather<<<NB_G, 256, 0, stream>>>(xh, aggb, rowstart, deg, csr, NN);
    k_mlp<<<NT, 256, 0, stream>>>(aggb, hb0, Wt1h, Wt2h, A1f, B1f, b2, NN);
    // layer 1: hb0 -> hb1
    k_gather<<<NB_G, 256, 0, stream>>>(hb0, aggb, rowstart, deg, csr, NN);
    k_mlp<<<NT, 256, 0, stream>>>(aggb, hb1, Wt1h + HH * HH, Wt2h + HH * HH,
                                  A1f + HH, B1f + HH, b2 + HH, NN);
    // layer 2: hb1 -> hb0
    k_gather<<<NB_G, 256, 0, stream>>>(hb1, aggb, rowstart, deg, csr, NN);
    k_mlp<<<NT, 256, 0, stream>>>(aggb, hb0, Wt1h + 2 * HH * HH, Wt2h + 2 * HH * HH,
                                  A1f + 2 * HH, B1f + 2 * HH, b2 + 2 * HH, NN);
    // head
    k_head<<<NT, 256, 0, stream>>>(hb0, lw1t, lw2t, lb1, lb2, out, NN);
}

// Round 5
// 343.721 us; speedup vs baseline: 2.0457x; 1.0015x over previous
//
#include <hip/hip_runtime.h>
#include <hip/hip_bf16.h>
#include <math.h>

// Problem constants (from reference)
#define NN 50000
#define EE 800000
#define HH 128
#define LL 3
#define CC 47

#define SCAN_NB ((NN + 255) / 256)  // 196 blocks for the hierarchical scan

typedef _Float16 half8  __attribute__((ext_vector_type(8)));
typedef _Float16 half2v __attribute__((ext_vector_type(2)));
typedef float    f32x4  __attribute__((ext_vector_type(4)));

__device__ __forceinline__ f32x4 mfma16(half8 a, half8 b, f32x4 c) {
    return __builtin_amdgcn_mfma_f32_16x16x32_f16(a, b, c, 0, 0, 0);
}

// ---------------- CSR build ----------------
__global__ void k_count(const int* __restrict__ ei, int* __restrict__ deg) {
    int e = blockIdx.x * blockDim.x + threadIdx.x;
    if (e < EE) atomicAdd(&deg[ei[EE + e]], 1);
}

// hierarchical scan, stage 1: per-256-block sums (coalesced)
__global__ __launch_bounds__(256) void k_blocksum(const int* __restrict__ deg,
                                                  int* __restrict__ blocksum) {
    __shared__ int ws[4];
    const int t = threadIdx.x;
    const int idx = blockIdx.x * 256 + t;
    int v = (idx < NN) ? deg[idx] : 0;
#pragma unroll
    for (int off = 32; off > 0; off >>= 1) v += __shfl_down(v, off, 64);
    if ((t & 63) == 0) ws[t >> 6] = v;
    __syncthreads();
    if (t == 0) blocksum[blockIdx.x] = ws[0] + ws[1] + ws[2] + ws[3];
}

// stage 2: scan the 196 block sums (one block)
__global__ __launch_bounds__(256) void k_scanbs(const int* __restrict__ blocksum,
                                                int* __restrict__ blockoff) {
    __shared__ int ps[256];
    const int t = threadIdx.x;
    int v = (t < SCAN_NB) ? blocksum[t] : 0;
    ps[t] = v;
    __syncthreads();
#pragma unroll
    for (int off = 1; off < 256; off <<= 1) {
        int u = (t >= off) ? ps[t - off] : 0;
        __syncthreads();
        ps[t] += u;
        __syncthreads();
    }
    if (t < SCAN_NB) blockoff[t] = ps[t] - v;  // exclusive
}

// stage 3: per-block exclusive scan + block offset -> rowstart, cursor
__global__ __launch_bounds__(256) void k_apply(const int* __restrict__ deg,
                                               const int* __restrict__ blockoff,
                                               int* __restrict__ rowstart,
                                               int* __restrict__ cursor) {
    __shared__ int ps[256];
    const int t = threadIdx.x;
    const int idx = blockIdx.x * 256 + t;
    int v = (idx < NN) ? deg[idx] : 0;
    ps[t] = v;
    __syncthreads();
#pragma unroll
    for (int off = 1; off < 256; off <<= 1) {
        int u = (t >= off) ? ps[t - off] : 0;
        __syncthreads();
        ps[t] += u;
        __syncthreads();
    }
    if (idx < NN) {
        const int r = blockoff[blockIdx.x] + ps[t] - v;
        rowstart[idx] = r;
        cursor[idx] = r;
    }
}

// XCD-partitioned fill: block b (round-robins to XCD b&7) handles only dst in
// its 1/8 node range -> each csr cache line is written by ONE XCD's L2.
__global__ __launch_bounds__(256) void k_fill(const int* __restrict__ ei,
                                              int* __restrict__ cursor,
                                              int* __restrict__ csr) {
    const int part = blockIdx.x & 7;
    const int chunk = blockIdx.x >> 3;
    const int nchunks = gridDim.x >> 3;
    const int lo = part * (NN / 8);  // 6250
    const int hi = (part == 7) ? NN : lo + (NN / 8);
    for (int e = chunk * 256 + threadIdx.x; e < EE; e += nchunks * 256) {
        const int d = ei[EE + e];
        if (d >= lo && d < hi) {
            const int pos = atomicAdd(&cursor[d], 1);
            csr[pos] = ei[e];  // src
        }
    }
}

// ---------------- prep: fp16 convert, weight transpose, BN fold ----------------
__global__ void k_prep(const float* __restrict__ x, const float* __restrict__ W1,
                       const float* __restrict__ W2, const float* __restrict__ lw1,
                       const float* __restrict__ lw2, const float* __restrict__ b1,
                       const float* __restrict__ gamma, const float* __restrict__ beta,
                       const float* __restrict__ bnm, const float* __restrict__ bnv,
                       _Float16* __restrict__ xh, _Float16* __restrict__ Wt1h,
                       _Float16* __restrict__ Wt2h, _Float16* __restrict__ lw1t,
                       _Float16* __restrict__ lw2t, float* __restrict__ A1f,
                       float* __restrict__ B1f) {
    long i = (long)blockIdx.x * blockDim.x + threadIdx.x;
    const long P0 = (long)NN * HH;
    const long P1 = P0 + (long)LL * HH * HH;
    const long P2 = P1 + (long)LL * HH * HH;
    const long P3 = P2 + HH * HH;
    const long P4 = P3 + 48 * HH;
    const long P5 = P4 + LL * HH;
    if (i < P0) {
        xh[i] = (_Float16)x[i];
    } else if (i < P1) {
        long j = i - P0;
        int l = (int)(j / (HH * HH));
        int n = (int)((j / HH) % HH);
        int k = (int)(j % HH);
        Wt1h[l * HH * HH + n * HH + k] = (_Float16)W1[l * HH * HH + k * HH + n];
    } else if (i < P2) {
        long j = i - P1;
        int l = (int)(j / (HH * HH));
        int n = (int)((j / HH) % HH);
        int k = (int)(j % HH);
        Wt2h[l * HH * HH + n * HH + k] = (_Float16)W2[l * HH * HH + k * HH + n];
    } else if (i < P3) {
        long j = i - P2;
        int n = (int)(j / HH), k = (int)(j % HH);
        lw1t[n * HH + k] = (_Float16)lw1[k * HH + n];
    } else if (i < P4) {
        long j = i - P3;
        int n = (int)(j / HH), k = (int)(j % HH);
        lw2t[n * HH + k] = (_Float16)((n < CC) ? lw2[k * CC + n] : 0.f);
    } else if (i < P5) {
        long j = i - P4;
        float s = gamma[j] * rsqrtf(bnv[j] + 1e-5f);
        A1f[j] = s;
        B1f[j] = (b1[j] - bnm[j]) * s + beta[j];
    }
}

// ---------------- gather: agg[i] = h[i] + sum_{j in N(i)} h[j], fp16 ----------------
// 16 lanes per node-pair slice; each 16-lane group owns TWO adjacent nodes with
// interleaved edge loops -> 2x independent load chains (x unroll 4 = ~8 in flight).
__global__ __launch_bounds__(256, 6) void k_gather(
    const _Float16* __restrict__ hin, _Float16* __restrict__ agg,
    const int* __restrict__ rowstart, const int* __restrict__ degs,
    const int* __restrict__ csr, int nn) {
    const int grp = (blockIdx.x * 256 + threadIdx.x) >> 4;
    const int fo = (threadIdx.x & 15) * 8;  // feature offset
    const int n0 = grp * 2;
    const int n1 = n0 + 1;
    if (n0 >= nn) return;
    const bool has1 = (n1 < nn);

    float a0[8], a1[8];
    half8 h0 = *(const half8*)(hin + (size_t)n0 * HH + fo);
#pragma unroll
    for (int j = 0; j < 8; ++j) a0[j] = (float)h0[j];
    if (has1) {
        half8 h1 = *(const half8*)(hin + (size_t)n1 * HH + fo);
#pragma unroll
        for (int j = 0; j < 8; ++j) a1[j] = (float)h1[j];
    } else {
#pragma unroll
        for (int j = 0; j < 8; ++j) a1[j] = 0.f;
    }

    const int e0 = rowstart[n0];
    const int d0 = degs[n0];
    const int e1 = has1 ? rowstart[n1] : 0;
    const int d1 = has1 ? degs[n1] : 0;
    const int m = (d0 < d1) ? d0 : d1;

    // interleaved main loop: two independent load chains
#pragma unroll 4
    for (int i = 0; i < m; ++i) {
        const int s0 = csr[e0 + i];
        const int s1 = csr[e1 + i];
        half8 v0 = *(const half8*)(hin + (size_t)s0 * HH + fo);
        half8 v1 = *(const half8*)(hin + (size_t)s1 * HH + fo);
#pragma unroll
        for (int j = 0; j < 8; ++j) a0[j] += (float)v0[j];
#pragma unroll
        for (int j = 0; j < 8; ++j) a1[j] += (float)v1[j];
    }
    // drains
#pragma unroll 4
    for (int i = m; i < d0; ++i) {
        const int s0 = csr[e0 + i];
        half8 v0 = *(const half8*)(hin + (size_t)s0 * HH + fo);
#pragma unroll
        for (int j = 0; j < 8; ++j) a0[j] += (float)v0[j];
    }
#pragma unroll 4
    for (int i = m; i < d1; ++i) {
        const int s1 = csr[e1 + i];
        half8 v1 = *(const half8*)(hin + (size_t)s1 * HH + fo);
#pragma unroll
        for (int j = 0; j < 8; ++j) a1[j] += (float)v1[j];
    }

    half8 o0, o1;
#pragma unroll
    for (int j = 0; j < 8; ++j) o0[j] = (_Float16)a0[j];
    *(half8*)(agg + (size_t)n0 * HH + fo) = o0;
    if (has1) {
#pragma unroll
        for (int j = 0; j < 8; ++j) o1[j] = (_Float16)a1[j];
        *(half8*)(agg + (size_t)n1 * HH + fo) = o1;
    }
}

// ---------------- MLP: GEMM1 + foldedBN + relu + GEMM2 + relu ----------------
__global__ __launch_bounds__(256) void k_mlp(
    const _Float16* __restrict__ aggh, _Float16* __restrict__ hout,
    const _Float16* __restrict__ Wt1, const _Float16* __restrict__ Wt2,
    const float* __restrict__ A1, const float* __restrict__ B1,
    const float* __restrict__ b2, int nn) {
    __shared__ _Float16 Ab[64 * 136];
    __shared__ _Float16 Ws[128 * 136];
    const int tid = threadIdx.x;
    const int wave = tid >> 6, lane = tid & 63;
    const int q = lane >> 4, l15 = lane & 15;
    const int tile0 = blockIdx.x * 64;

    // stage Wt1 -> LDS
    {
        int r = tid >> 4;
        const int c = (tid & 15) * 8;
#pragma unroll
        for (int it = 0; it < 8; ++it, r += 16)
            *(half8*)(Ws + r * 136 + c) = *(const half8*)(Wt1 + r * 128 + c);
    }
    // stage A rows from aggh
    {
        int r = tid >> 4;
        const int c = (tid & 15) * 8;
#pragma unroll
        for (int it = 0; it < 4; ++it, r += 16) {
            const int g = tile0 + r;
            half8 v = {0, 0, 0, 0, 0, 0, 0, 0};
            if (g < nn) v = *(const half8*)(aggh + (size_t)g * HH + c);
            *(half8*)(Ab + r * 136 + c) = v;
        }
    }
    __syncthreads();

    // GEMM1
    f32x4 acc[4][2];
#pragma unroll
    for (int s = 0; s < 4; ++s)
#pragma unroll
        for (int t = 0; t < 2; ++t) acc[s][t] = (f32x4){0.f, 0.f, 0.f, 0.f};
#pragma unroll
    for (int kt = 0; kt < 4; ++kt) {
        const int ko = kt * 32 + q * 8;
        half8 a0 = *(const half8*)(Ab + (0 * 16 + l15) * 136 + ko);
        half8 a1 = *(const half8*)(Ab + (1 * 16 + l15) * 136 + ko);
        half8 a2 = *(const half8*)(Ab + (2 * 16 + l15) * 136 + ko);
        half8 a3 = *(const half8*)(Ab + (3 * 16 + l15) * 136 + ko);
        half8 bb0 = *(const half8*)(Ws + (wave * 32 + 0 * 16 + l15) * 136 + ko);
        half8 bb1 = *(const half8*)(Ws + (wave * 32 + 1 * 16 + l15) * 136 + ko);
        acc[0][0] = mfma16(a0, bb0, acc[0][0]);
        acc[1][0] = mfma16(a1, bb0, acc[1][0]);
        acc[2][0] = mfma16(a2, bb0, acc[2][0]);
        acc[3][0] = mfma16(a3, bb0, acc[3][0]);
        acc[0][1] = mfma16(a0, bb1, acc[0][1]);
        acc[1][1] = mfma16(a1, bb1, acc[1][1]);
        acc[2][1] = mfma16(a2, bb1, acc[2][1]);
        acc[3][1] = mfma16(a3, bb1, acc[3][1]);
    }
    __syncthreads();

    // stage Wt2
    {
        int r = tid >> 4;
        const int c = (tid & 15) * 8;
#pragma unroll
        for (int it = 0; it < 8; ++it, r += 16)
            *(half8*)(Ws + r * 136 + c) = *(const half8*)(Wt2 + r * 128 + c);
    }
    // epilogue1: folded BN + relu -> Z into Ab
#pragma unroll
    for (int t = 0; t < 2; ++t) {
        const int col = wave * 32 + t * 16 + l15;
        const float sc = A1[col], sh = B1[col];
#pragma unroll
        for (int s = 0; s < 4; ++s)
#pragma unroll
            for (int r = 0; r < 4; ++r) {
                const int row = s * 16 + q * 4 + r;
                float v = acc[s][t][r] * sc + sh;
                Ab[row * 136 + col] = (_Float16)fmaxf(v, 0.f);
            }
    }
    __syncthreads();

    // GEMM2
#pragma unroll
    for (int s = 0; s < 4; ++s)
#pragma unroll
        for (int t = 0; t < 2; ++t) acc[s][t] = (f32x4){0.f, 0.f, 0.f, 0.f};
#pragma unroll
    for (int kt = 0; kt < 4; ++kt) {
        const int ko = kt * 32 + q * 8;
        half8 a0 = *(const half8*)(Ab + (0 * 16 + l15) * 136 + ko);
        half8 a1 = *(const half8*)(Ab + (1 * 16 + l15) * 136 + ko);
        half8 a2 = *(const half8*)(Ab + (2 * 16 + l15) * 136 + ko);
        half8 a3 = *(const half8*)(Ab + (3 * 16 + l15) * 136 + ko);
        half8 bb0 = *(const half8*)(Ws + (wave * 32 + 0 * 16 + l15) * 136 + ko);
        half8 bb1 = *(const half8*)(Ws + (wave * 32 + 1 * 16 + l15) * 136 + ko);
        acc[0][0] = mfma16(a0, bb0, acc[0][0]);
        acc[1][0] = mfma16(a1, bb0, acc[1][0]);
        acc[2][0] = mfma16(a2, bb0, acc[2][0]);
        acc[3][0] = mfma16(a3, bb0, acc[3][0]);
        acc[0][1] = mfma16(a0, bb1, acc[0][1]);
        acc[1][1] = mfma16(a1, bb1, acc[1][1]);
        acc[2][1] = mfma16(a2, bb1, acc[2][1]);
        acc[3][1] = mfma16(a3, bb1, acc[3][1]);
    }
    // epilogue2: +b2, relu, store
#pragma unroll
    for (int t = 0; t < 2; ++t) {
        const int col = wave * 32 + t * 16 + l15;
        const float bb = b2[col];
#pragma unroll
        for (int s = 0; s < 4; ++s)
#pragma unroll
            for (int r = 0; r < 4; ++r) {
                const int row = s * 16 + q * 4 + r;
                const int g = tile0 + row;
                if (g < nn) {
                    float v = fmaxf(acc[s][t][r] + bb, 0.f);
                    hout[(size_t)g * HH + col] = (_Float16)v;
                }
            }
    }
}

// ---------------- layer-2 MLP fused with head: h3 never leaves LDS ----------------
__global__ __launch_bounds__(256) void k_mlp_head(
    const _Float16* __restrict__ aggh,
    const _Float16* __restrict__ Wt1, const _Float16* __restrict__ Wt2,
    const float* __restrict__ A1, const float* __restrict__ B1,
    const float* __restrict__ b2,
    const _Float16* __restrict__ lw1t, const _Float16* __restrict__ lw2t,
    const float* __restrict__ lb1, const float* __restrict__ lb2,
    float* __restrict__ out, int nn) {
    __shared__ _Float16 Ab[64 * 136];
    __shared__ _Float16 Ws[128 * 136];
    const int tid = threadIdx.x;
    const int wave = tid >> 6, lane = tid & 63;
    const int q = lane >> 4, l15 = lane & 15;
    const int tile0 = blockIdx.x * 64;
    const int stg_c = (tid & 15) * 8;

    // stage Wt1 + A rows
    {
        int r = tid >> 4;
#pragma unroll
        for (int it = 0; it < 8; ++it, r += 16)
            *(half8*)(Ws + r * 136 + stg_c) = *(const half8*)(Wt1 + r * 128 + stg_c);
    }
    {
        int r = tid >> 4;
#pragma unroll
        for (int it = 0; it < 4; ++it, r += 16) {
            const int g = tile0 + r;
            half8 v = {0, 0, 0, 0, 0, 0, 0, 0};
            if (g < nn) v = *(const half8*)(aggh + (size_t)g * HH + stg_c);
            *(half8*)(Ab + r * 136 + stg_c) = v;
        }
    }
    __syncthreads();

    f32x4 acc[4][2];
    // ---- GEMM1 (agg @ W1) ----
#pragma unroll
    for (int s = 0; s < 4; ++s)
#pragma unroll
        for (int t = 0; t < 2; ++t) acc[s][t] = (f32x4){0.f, 0.f, 0.f, 0.f};
#pragma unroll
    for (int kt = 0; kt < 4; ++kt) {
        const int ko = kt * 32 + q * 8;
        half8 a0 = *(const half8*)(Ab + (0 * 16 + l15) * 136 + ko);
        half8 a1 = *(const half8*)(Ab + (1 * 16 + l15) * 136 + ko);
        half8 a2 = *(const half8*)(Ab + (2 * 16 + l15) * 136 + ko);
        half8 a3 = *(const half8*)(Ab + (3 * 16 + l15) * 136 + ko);
        half8 bb0 = *(const half8*)(Ws + (wave * 32 + 0 * 16 + l15) * 136 + ko);
        half8 bb1 = *(const half8*)(Ws + (wave * 32 + 1 * 16 + l15) * 136 + ko);
        acc[0][0] = mfma16(a0, bb0, acc[0][0]);
        acc[1][0] = mfma16(a1, bb0, acc[1][0]);
        acc[2][0] = mfma16(a2, bb0, acc[2][0]);
        acc[3][0] = mfma16(a3, bb0, acc[3][0]);
        acc[0][1] = mfma16(a0, bb1, acc[0][1]);
        acc[1][1] = mfma16(a1, bb1, acc[1][1]);
        acc[2][1] = mfma16(a2, bb1, acc[2][1]);
        acc[3][1] = mfma16(a3, bb1, acc[3][1]);
    }
    __syncthreads();
    // stage Wt2; BN+relu -> Ab
    {
        int r = tid >> 4;
#pragma unroll
        for (int it = 0; it < 8; ++it, r += 16)
            *(half8*)(Ws + r * 136 + stg_c) = *(const half8*)(Wt2 + r * 128 + stg_c);
    }
#pragma unroll
    for (int t = 0; t < 2; ++t) {
        const int col = wave * 32 + t * 16 + l15;
        const float sc = A1[col], sh = B1[col];
#pragma unroll
        for (int s = 0; s < 4; ++s)
#pragma unroll
            for (int r = 0; r < 4; ++r) {
                const int row = s * 16 + q * 4 + r;
                float v = acc[s][t][r] * sc + sh;
                Ab[row * 136 + col] = (_Float16)fmaxf(v, 0.f);
            }
    }
    __syncthreads();

    // ---- GEMM2 (Z @ W2) ----
#pragma unroll
    for (int s = 0; s < 4; ++s)
#pragma unroll
        for (int t = 0; t < 2; ++t) acc[s][t] = (f32x4){0.f, 0.f, 0.f, 0.f};
#pragma unroll
    for (int kt = 0; kt < 4; ++kt) {
        const int ko = kt * 32 + q * 8;
        half8 a0 = *(const half8*)(Ab + (0 * 16 + l15) * 136 + ko);
        half8 a1 = *(const half8*)(Ab + (1 * 16 + l15) * 136 + ko);
        half8 a2 = *(const half8*)(Ab + (2 * 16 + l15) * 136 + ko);
        half8 a3 = *(const half8*)(Ab + (3 * 16 + l15) * 136 + ko);
        half8 bb0 = *(const half8*)(Ws + (wave * 32 + 0 * 16 + l15) * 136 + ko);
        half8 bb1 = *(const half8*)(Ws + (wave * 32 + 1 * 16 + l15) * 136 + ko);
        acc[0][0] = mfma16(a0, bb0, acc[0][0]);
        acc[1][0] = mfma16(a1, bb0, acc[1][0]);
        acc[2][0] = mfma16(a2, bb0, acc[2][0]);
        acc[3][0] = mfma16(a3, bb0, acc[3][0]);
        acc[0][1] = mfma16(a0, bb1, acc[0][1]);
        acc[1][1] = mfma16(a1, bb1, acc[1][1]);
        acc[2][1] = mfma16(a2, bb1, acc[2][1]);
        acc[3][1] = mfma16(a3, bb1, acc[3][1]);
    }
    __syncthreads();  // GEMM2 reads of Ab/Ws done
    // stage lw1t; h3 = relu(acc + b2) -> Ab
    {
        int r = tid >> 4;
#pragma unroll
        for (int it = 0; it < 8; ++it, r += 16)
            *(half8*)(Ws + r * 136 + stg_c) = *(const half8*)(lw1t + r * 128 + stg_c);
    }
#pragma unroll
    for (int t = 0; t < 2; ++t) {
        const int col = wave * 32 + t * 16 + l15;
        const float bb = b2[col];
#pragma unroll
        for (int s = 0; s < 4; ++s)
#pragma unroll
            for (int r = 0; r < 4; ++r) {
                const int row = s * 16 + q * 4 + r;
                Ab[row * 136 + col] = (_Float16)fmaxf(acc[s][t][r] + bb, 0.f);
            }
    }
    __syncthreads();

    // ---- GEMM3 (h3 @ lw1) ----
#pragma unroll
    for (int s = 0; s < 4; ++s)
#pragma unroll
        for (int t = 0; t < 2; ++t) acc[s][t] = (f32x4){0.f, 0.f, 0.f, 0.f};
#pragma unroll
    for (int kt = 0; kt < 4; ++kt) {
        const int ko = kt * 32 + q * 8;
        half8 a0 = *(const half8*)(Ab + (0 * 16 + l15) * 136 + ko);
        half8 a1 = *(const half8*)(Ab + (1 * 16 + l15) * 136 + ko);
        half8 a2 = *(const half8*)(Ab + (2 * 16 + l15) * 136 + ko);
        half8 a3 = *(const half8*)(Ab + (3 * 16 + l15) * 136 + ko);
        half8 bb0 = *(const half8*)(Ws + (wave * 32 + 0 * 16 + l15) * 136 + ko);
        half8 bb1 = *(const half8*)(Ws + (wave * 32 + 1 * 16 + l15) * 136 + ko);
        acc[0][0] = mfma16(a0, bb0, acc[0][0]);
        acc[1][0] = mfma16(a1, bb0, acc[1][0]);
        acc[2][0] = mfma16(a2, bb0, acc[2][0]);
        acc[3][0] = mfma16(a3, bb0, acc[3][0]);
        acc[0][1] = mfma16(a0, bb1, acc[0][1]);
        acc[1][1] = mfma16(a1, bb1, acc[1][1]);
        acc[2][1] = mfma16(a2, bb1, acc[2][1]);
        acc[3][1] = mfma16(a3, bb1, acc[3][1]);
    }
    __syncthreads();
    // stage lw2t (48 rows); h4 = relu(acc + lb1) -> Ab
    {
        int r = tid >> 4;
#pragma unroll
        for (int it = 0; it < 3; ++it, r += 16)
            *(half8*)(Ws + r * 136 + stg_c) = *(const half8*)(lw2t + r * 128 + stg_c);
    }
#pragma unroll
    for (int t = 0; t < 2; ++t) {
        const int col = wave * 32 + t * 16 + l15;
        const float bb = lb1[col];
#pragma unroll
        for (int s = 0; s < 4; ++s)
#pragma unroll
            for (int r = 0; r < 4; ++r) {
                const int row = s * 16 + q * 4 + r;
                Ab[row * 136 + col] = (_Float16)fmaxf(acc[s][t][r] + bb, 0.f);
            }
    }
    __syncthreads();

    // ---- GEMM4 (h4 @ lw2, 48 cols, waves 0..2) ----
    f32x4 acc2[4];
#pragma unroll
    for (int s = 0; s < 4; ++s) acc2[s] = (f32x4){0.f, 0.f, 0.f, 0.f};
    if (wave < 3) {
#pragma unroll
        for (int kt = 0; kt < 4; ++kt) {
            const int ko = kt * 32 + q * 8;
            half8 a0 = *(const half8*)(Ab + (0 * 16 + l15) * 136 + ko);
            half8 a1 = *(const half8*)(Ab + (1 * 16 + l15) * 136 + ko);
            half8 a2 = *(const half8*)(Ab + (2 * 16 + l15) * 136 + ko);
            half8 a3 = *(const half8*)(Ab + (3 * 16 + l15) * 136 + ko);
            half8 bb = *(const half8*)(Ws + (wave * 16 + l15) * 136 + ko);
            acc2[0] = mfma16(a0, bb, acc2[0]);
            acc2[1] = mfma16(a1, bb, acc2[1]);
            acc2[2] = mfma16(a2, bb, acc2[2]);
            acc2[3] = mfma16(a3, bb, acc2[3]);
        }
    }
    __syncthreads();  // all reads of Ab done before aliasing as float buffer

    float* Lb = (float*)Ab;  // 64 x 49 floats = 12.5 KB
    if (wave < 3) {
        const int col = wave * 16 + l15;
        const float bb = (col < CC) ? lb2[col] : 0.f;
#pragma unroll
        for (int s = 0; s < 4; ++s)
#pragma unroll
            for (int r = 0; r < 4; ++r) {
                const int row = s * 16 + q * 4 + r;
                Lb[row * 49 + col] = acc2[s][r] + bb;
            }
    }
    __syncthreads();

    // log_softmax: one thread per row
    if (tid < 64) {
        const int g = tile0 + tid;
        if (g < nn) {
            float m = -1e30f;
            for (int c = 0; c < CC; ++c) m = fmaxf(m, Lb[tid * 49 + c]);
            float ssum = 0.f;
            for (int c = 0; c < CC; ++c) ssum += expf(Lb[tid * 49 + c] - m);
            const float ls = logf(ssum) + m;
            for (int c = 0; c < CC; ++c) out[(size_t)g * CC + c] = Lb[tid * 49 + c] - ls;
        }
    }
}

// ---------------- host ----------------
extern "C" void kernel_launch(void* const* d_in, const int* in_sizes, int n_in,
                              void* d_out, int out_size, void* d_ws, size_t ws_size,
                              hipStream_t stream) {
    const float* x     = (const float*)d_in[0];
    const int*   ei    = (const int*)d_in[1];
    const float* W1    = (const float*)d_in[2];
    const float* b1    = (const float*)d_in[3];
    const float* gamma = (const float*)d_in[4];
    const float* beta  = (const float*)d_in[5];
    const float* bnm   = (const float*)d_in[6];
    const float* bnv   = (const float*)d_in[7];
    const float* W2    = (const float*)d_in[8];
    const float* b2    = (const float*)d_in[9];
    const float* lw1   = (const float*)d_in[10];
    const float* lb1   = (const float*)d_in[11];
    const float* lw2   = (const float*)d_in[12];
    const float* lb2   = (const float*)d_in[13];
    float* out = (float*)d_out;

    char* p = (char*)d_ws;
    auto carve = [&](size_t bytes) -> char* {
        char* r = p;
        p += (bytes + 255) & ~(size_t)255;
        return r;
    };
    int* deg      = (int*)carve((size_t)NN * 4);
    int* rowstart = (int*)carve((size_t)NN * 4);
    int* cursor   = (int*)carve((size_t)NN * 4);
    int* csr      = (int*)carve((size_t)EE * 4);
    int* blocksum = (int*)carve((size_t)SCAN_NB * 4);
    int* blockoff = (int*)carve((size_t)SCAN_NB * 4);
    _Float16* Wt1h = (_Float16*)carve((size_t)LL * HH * HH * 2);
    _Float16* Wt2h = (_Float16*)carve((size_t)LL * HH * HH * 2);
    _Float16* lw1t = (_Float16*)carve((size_t)HH * HH * 2);
    _Float16* lw2t = (_Float16*)carve((size_t)48 * HH * 2);
    float* A1f = (float*)carve((size_t)LL * HH * 4);
    float* B1f = (float*)carve((size_t)LL * HH * 4);
    _Float16* xh   = (_Float16*)carve((size_t)NN * HH * 2);
    _Float16* hb0  = (_Float16*)carve((size_t)NN * HH * 2);
    _Float16* hb1  = (_Float16*)carve((size_t)NN * HH * 2);
    _Float16* aggb = (_Float16*)carve((size_t)NN * HH * 2);

    // CSR build
    hipMemsetAsync(deg, 0, (size_t)NN * 4, stream);
    k_count<<<(EE + 255) / 256, 256, 0, stream>>>(ei, deg);
    k_blocksum<<<SCAN_NB, 256, 0, stream>>>(deg, blocksum);
    k_scanbs<<<1, 256, 0, stream>>>(blocksum, blockoff);
    k_apply<<<SCAN_NB, 256, 0, stream>>>(deg, blockoff, rowstart, cursor);
    k_fill<<<2048, 256, 0, stream>>>(ei, cursor, csr);

    // prep
    const long total = (long)NN * HH + 2L * LL * HH * HH + (long)HH * HH + 48L * HH + (long)LL * HH;
    k_prep<<<(int)((total + 255) / 256), 256, 0, stream>>>(
        x, W1, W2, lw1, lw2, b1, gamma, beta, bnm, bnv,
        xh, Wt1h, Wt2h, lw1t, lw2t, A1f, B1f);

    const int NB_G = (NN * 8 + 255) / 256;  // two nodes per 16-lane group
    const int NT = (NN + 63) / 64;          // 782 tiles

    // layer 0: xh -> hb0
    k_gather<<<NB_G, 256, 0, stream>>>(xh, aggb, rowstart, deg, csr, NN);
    k_mlp<<<NT, 256, 0, stream>>>(aggb, hb0, Wt1h, Wt2h, A1f, B1f, b2, NN);
    // layer 1: hb0 -> hb1
    k_gather<<<NB_G, 256, 0, stream>>>(hb0, aggb, rowstart, deg, csr, NN);
    k_mlp<<<NT, 256, 0, stream>>>(aggb, hb1, Wt1h + HH * HH, Wt2h + HH * HH,
                                  A1f + HH, B1f + HH, b2 + HH, NN);
    // layer 2 + head fused: hb1 -> out
    k_gather<<<NB_G, 256, 0, stream>>>(hb1, aggb, rowstart, deg, csr, NN);
    k_mlp_head<<<NT, 256, 0, stream>>>(aggb, Wt1h + 2 * HH * HH, Wt2h + 2 * HH * HH,
                                       A1f + 2 * HH, B1f + 2 * HH, b2 + 2 * HH,
                                       lw1t, lw2t, lb1, lb2, out, NN);
}

// Round 7
// 322.036 us; speedup vs baseline: 2.1835x; 1.0673x over previous
//
#include <hip/hip_runtime.h>
#include <math.h>

// Problem constants
#define NN 50000
#define EE 800000
#define HH 128
#define LL 3
#define CC 47
#define SCAN_NB 196          // ceil(NN/256)
#define CNT_B 3125           // blocks for edge counting in k_count_prep
#define NT_TILES 782         // ceil(NN/64)

typedef _Float16 half8 __attribute__((ext_vector_type(8)));
typedef float    f32x4 __attribute__((ext_vector_type(4)));

__device__ __forceinline__ f32x4 mfma16(half8 a, half8 b, f32x4 c) {
    return __builtin_amdgcn_mfma_f32_16x16x32_f16(a, b, c, 0, 0, 0);
}

// ---------------- fused count + prep ----------------
__global__ void k_count_prep(const int* __restrict__ ei, int* __restrict__ deg,
                             const float* __restrict__ x, const float* __restrict__ W1,
                             const float* __restrict__ W2, const float* __restrict__ lw1,
                             const float* __restrict__ lw2, const float* __restrict__ b1,
                             const float* __restrict__ gamma, const float* __restrict__ beta,
                             const float* __restrict__ bnm, const float* __restrict__ bnv,
                             _Float16* __restrict__ xh, _Float16* __restrict__ Wt1h,
                             _Float16* __restrict__ Wt2h, _Float16* __restrict__ lw1t,
                             _Float16* __restrict__ lw2t, float* __restrict__ A1f,
                             float* __restrict__ B1f) {
    if (blockIdx.x < CNT_B) {
        int e = blockIdx.x * 256 + threadIdx.x;
        if (e < EE) atomicAdd(&deg[ei[EE + e]], 1);
        return;
    }
    long i = (long)(blockIdx.x - CNT_B) * 256 + threadIdx.x;
    const long P0 = (long)NN * HH;
    const long P1 = P0 + (long)LL * HH * HH;
    const long P2 = P1 + (long)LL * HH * HH;
    const long P3 = P2 + HH * HH;
    const long P4 = P3 + 48 * HH;
    const long P5 = P4 + LL * HH;
    if (i < P0) {
        xh[i] = (_Float16)x[i];
    } else if (i < P1) {
        long j = i - P0;
        int l = (int)(j / (HH * HH));
        int n = (int)((j / HH) % HH);
        int k = (int)(j % HH);
        Wt1h[l * HH * HH + n * HH + k] = (_Float16)W1[l * HH * HH + k * HH + n];
    } else if (i < P2) {
        long j = i - P1;
        int l = (int)(j / (HH * HH));
        int n = (int)((j / HH) % HH);
        int k = (int)(j % HH);
        Wt2h[l * HH * HH + n * HH + k] = (_Float16)W2[l * HH * HH + k * HH + n];
    } else if (i < P3) {
        long j = i - P2;
        int n = (int)(j / HH), k = (int)(j % HH);
        lw1t[n * HH + k] = (_Float16)lw1[k * HH + n];
    } else if (i < P4) {
        long j = i - P3;
        int n = (int)(j / HH), k = (int)(j % HH);
        lw2t[n * HH + k] = (_Float16)((n < CC) ? lw2[k * CC + n] : 0.f);
    } else if (i < P5) {
        long j = i - P4;
        float s = gamma[j] * rsqrtf(bnv[j] + 1e-5f);
        A1f[j] = s;
        B1f[j] = (b1[j] - bnm[j]) * s + beta[j];
    }
}

// ---------------- hierarchical scan ----------------
__global__ __launch_bounds__(256) void k_blocksum(const int* __restrict__ deg,
                                                  int* __restrict__ blocksum) {
    __shared__ int ws[4];
    const int t = threadIdx.x;
    const int idx = blockIdx.x * 256 + t;
    int v = (idx < NN) ? deg[idx] : 0;
#pragma unroll
    for (int off = 32; off > 0; off >>= 1) v += __shfl_down(v, off, 64);
    if ((t & 63) == 0) ws[t >> 6] = v;
    __syncthreads();
    if (t == 0) blocksum[blockIdx.x] = ws[0] + ws[1] + ws[2] + ws[3];
}

__global__ __launch_bounds__(256) void k_scanbs(const int* __restrict__ blocksum,
                                                int* __restrict__ blockoff) {
    __shared__ int ps[256];
    const int t = threadIdx.x;
    int v = (t < SCAN_NB) ? blocksum[t] : 0;
    ps[t] = v;
    __syncthreads();
#pragma unroll
    for (int off = 1; off < 256; off <<= 1) {
        int u = (t >= off) ? ps[t - off] : 0;
        __syncthreads();
        ps[t] += u;
        __syncthreads();
    }
    if (t < SCAN_NB) blockoff[t] = ps[t] - v;  // exclusive
}

__global__ __launch_bounds__(256) void k_apply(const int* __restrict__ deg,
                                               const int* __restrict__ blockoff,
                                               int* __restrict__ rowstart,
                                               int* __restrict__ cursor) {
    __shared__ int ps[256];
    const int t = threadIdx.x;
    const int idx = blockIdx.x * 256 + t;
    int v = (idx < NN) ? deg[idx] : 0;
    ps[t] = v;
    __syncthreads();
#pragma unroll
    for (int off = 1; off < 256; off <<= 1) {
        int u = (t >= off) ? ps[t - off] : 0;
        __syncthreads();
        ps[t] += u;
        __syncthreads();
    }
    if (idx < NN) {
        const int r = blockoff[blockIdx.x] + ps[t] - v;
        rowstart[idx] = r;
        cursor[idx] = r;
    }
}

// XCD-partitioned CSR fill (keeps each csr line within one XCD's L2)
__global__ __launch_bounds__(256) void k_fill(const int* __restrict__ ei,
                                              int* __restrict__ cursor,
                                              int* __restrict__ csr) {
    const int part = blockIdx.x & 7;
    const int chunk = blockIdx.x >> 3;
    const int nchunks = gridDim.x >> 3;
    const int lo = part * (NN / 8);
    const int hi = (part == 7) ? NN : lo + (NN / 8);
    for (int e = chunk * 256 + threadIdx.x; e < EE; e += nchunks * 256) {
        const int d = ei[EE + e];
        if (d >= lo && d < hi) {
            const int pos = atomicAdd(&cursor[d], 1);
            csr[pos] = ei[e];  // src
        }
    }
}

// ---------------- fused layer: gather -> GEMM1 -> BN+relu -> GEMM2 -> relu ----------------
// 64 nodes/block, 256 threads. Gather: 16 lanes/node, 16 concurrent nodes x 4 passes.
// Weights read per-fragment from global (L2-broadcast) -> LDS is just the 17.4KB A-tile.
__global__ __launch_bounds__(256, 4) void k_layer(
    const _Float16* __restrict__ hin, _Float16* __restrict__ hout,
    const _Float16* __restrict__ Wt1, const _Float16* __restrict__ Wt2,
    const float* __restrict__ A1, const float* __restrict__ B1,
    const float* __restrict__ b2, const int* __restrict__ rowstart,
    const int* __restrict__ degs, const int* __restrict__ csr) {
    __shared__ _Float16 Ab[64 * 136];
    const int tid = threadIdx.x;
    const int wave = tid >> 6, lane = tid & 63;
    const int q = lane >> 4, l15 = lane & 15;
    const int tile0 = blockIdx.x * 64;
    const int fo = (tid & 15) * 8;

    // preload GEMM1 B-fragments from global (completes during gather)
    half8 Bf[2][4];
#pragma unroll
    for (int t = 0; t < 2; ++t)
#pragma unroll
        for (int kt = 0; kt < 4; ++kt)
            Bf[t][kt] = *(const half8*)(Wt1 + (wave * 32 + t * 16 + l15) * 128 + kt * 32 + q * 8);

    // gather into LDS A-tile
#pragma unroll
    for (int pass = 0; pass < 4; ++pass) {
        const int r = pass * 16 + (tid >> 4);
        const int g = tile0 + r;
        float a[8];
        if (g < NN) {
            half8 hv = *(const half8*)(hin + (size_t)g * HH + fo);
#pragma unroll
            for (int j = 0; j < 8; ++j) a[j] = (float)hv[j];
            const int e0 = rowstart[g];
            const int d = degs[g];
#pragma unroll 4
            for (int e = e0; e < e0 + d; ++e) {
                const int s = csr[e];
                half8 v = *(const half8*)(hin + (size_t)s * HH + fo);
#pragma unroll
                for (int j = 0; j < 8; ++j) a[j] += (float)v[j];
            }
        } else {
#pragma unroll
            for (int j = 0; j < 8; ++j) a[j] = 0.f;
        }
        half8 o;
#pragma unroll
        for (int j = 0; j < 8; ++j) o[j] = (_Float16)a[j];
        *(half8*)(Ab + r * 136 + fo) = o;
    }
    __syncthreads();

    // GEMM1
    f32x4 acc[4][2];
#pragma unroll
    for (int s = 0; s < 4; ++s)
#pragma unroll
        for (int t = 0; t < 2; ++t) acc[s][t] = (f32x4){0.f, 0.f, 0.f, 0.f};
#pragma unroll
    for (int kt = 0; kt < 4; ++kt) {
        const int ko = kt * 32 + q * 8;
        half8 a0 = *(const half8*)(Ab + (0 * 16 + l15) * 136 + ko);
        half8 a1 = *(const half8*)(Ab + (1 * 16 + l15) * 136 + ko);
        half8 a2 = *(const half8*)(Ab + (2 * 16 + l15) * 136 + ko);
        half8 a3 = *(const half8*)(Ab + (3 * 16 + l15) * 136 + ko);
        acc[0][0] = mfma16(a0, Bf[0][kt], acc[0][0]);
        acc[1][0] = mfma16(a1, Bf[0][kt], acc[1][0]);
        acc[2][0] = mfma16(a2, Bf[0][kt], acc[2][0]);
        acc[3][0] = mfma16(a3, Bf[0][kt], acc[3][0]);
        acc[0][1] = mfma16(a0, Bf[1][kt], acc[0][1]);
        acc[1][1] = mfma16(a1, Bf[1][kt], acc[1][1]);
        acc[2][1] = mfma16(a2, Bf[1][kt], acc[2][1]);
        acc[3][1] = mfma16(a3, Bf[1][kt], acc[3][1]);
    }
    // preload GEMM2 B-fragments
#pragma unroll
    for (int t = 0; t < 2; ++t)
#pragma unroll
        for (int kt = 0; kt < 4; ++kt)
            Bf[t][kt] = *(const half8*)(Wt2 + (wave * 32 + t * 16 + l15) * 128 + kt * 32 + q * 8);
    __syncthreads();  // all GEMM1 reads of Ab done

    // epilogue1: folded BN + relu -> Z into Ab
#pragma unroll
    for (int t = 0; t < 2; ++t) {
        const int col = wave * 32 + t * 16 + l15;
        const float sc = A1[col], sh = B1[col];
#pragma unroll
        for (int s = 0; s < 4; ++s)
#pragma unroll
            for (int r = 0; r < 4; ++r) {
                const int row = s * 16 + q * 4 + r;
                float v = acc[s][t][r] * sc + sh;
                Ab[row * 136 + col] = (_Float16)fmaxf(v, 0.f);
            }
    }
    __syncthreads();

    // GEMM2
#pragma unroll
    for (int s = 0; s < 4; ++s)
#pragma unroll
        for (int t = 0; t < 2; ++t) acc[s][t] = (f32x4){0.f, 0.f, 0.f, 0.f};
#pragma unroll
    for (int kt = 0; kt < 4; ++kt) {
        const int ko = kt * 32 + q * 8;
        half8 a0 = *(const half8*)(Ab + (0 * 16 + l15) * 136 + ko);
        half8 a1 = *(const half8*)(Ab + (1 * 16 + l15) * 136 + ko);
        half8 a2 = *(const half8*)(Ab + (2 * 16 + l15) * 136 + ko);
        half8 a3 = *(const half8*)(Ab + (3 * 16 + l15) * 136 + ko);
        acc[0][0] = mfma16(a0, Bf[0][kt], acc[0][0]);
        acc[1][0] = mfma16(a1, Bf[0][kt], acc[1][0]);
        acc[2][0] = mfma16(a2, Bf[0][kt], acc[2][0]);
        acc[3][0] = mfma16(a3, Bf[0][kt], acc[3][0]);
        acc[0][1] = mfma16(a0, Bf[1][kt], acc[0][1]);
        acc[1][1] = mfma16(a1, Bf[1][kt], acc[1][1]);
        acc[2][1] = mfma16(a2, Bf[1][kt], acc[2][1]);
        acc[3][1] = mfma16(a3, Bf[1][kt], acc[3][1]);
    }
    // epilogue2: +b2, relu, store
#pragma unroll
    for (int t = 0; t < 2; ++t) {
        const int col = wave * 32 + t * 16 + l15;
        const float bb = b2[col];
#pragma unroll
        for (int s = 0; s < 4; ++s)
#pragma unroll
            for (int r = 0; r < 4; ++r) {
                const int row = s * 16 + q * 4 + r;
                const int g = tile0 + row;
                if (g < NN) {
                    float v = fmaxf(acc[s][t][r] + bb, 0.f);
                    hout[(size_t)g * HH + col] = (_Float16)v;
                }
            }
    }
}

// ---------------- fused layer-2 + head: gather -> MLP -> head GEMMs -> log_softmax ----------------
__global__ __launch_bounds__(256, 4) void k_layer_head(
    const _Float16* __restrict__ hin,
    const _Float16* __restrict__ Wt1, const _Float16* __restrict__ Wt2,
    const float* __restrict__ A1, const float* __restrict__ B1,
    const float* __restrict__ b2,
    const _Float16* __restrict__ lw1t, const _Float16* __restrict__ lw2t,
    const float* __restrict__ lb1, const float* __restrict__ lb2,
    float* __restrict__ out, const int* __restrict__ rowstart,
    const int* __restrict__ degs, const int* __restrict__ csr) {
    __shared__ _Float16 Ab[64 * 136];
    const int tid = threadIdx.x;
    const int wave = tid >> 6, lane = tid & 63;
    const int q = lane >> 4, l15 = lane & 15;
    const int tile0 = blockIdx.x * 64;
    const int fo = (tid & 15) * 8;

    half8 Bf[2][4];
#pragma unroll
    for (int t = 0; t < 2; ++t)
#pragma unroll
        for (int kt = 0; kt < 4; ++kt)
            Bf[t][kt] = *(const half8*)(Wt1 + (wave * 32 + t * 16 + l15) * 128 + kt * 32 + q * 8);

    // gather
#pragma unroll
    for (int pass = 0; pass < 4; ++pass) {
        const int r = pass * 16 + (tid >> 4);
        const int g = tile0 + r;
        float a[8];
        if (g < NN) {
            half8 hv = *(const half8*)(hin + (size_t)g * HH + fo);
#pragma unroll
            for (int j = 0; j < 8; ++j) a[j] = (float)hv[j];
            const int e0 = rowstart[g];
            const int d = degs[g];
#pragma unroll 4
            for (int e = e0; e < e0 + d; ++e) {
                const int s = csr[e];
                half8 v = *(const half8*)(hin + (size_t)s * HH + fo);
#pragma unroll
                for (int j = 0; j < 8; ++j) a[j] += (float)v[j];
            }
        } else {
#pragma unroll
            for (int j = 0; j < 8; ++j) a[j] = 0.f;
        }
        half8 o;
#pragma unroll
        for (int j = 0; j < 8; ++j) o[j] = (_Float16)a[j];
        *(half8*)(Ab + r * 136 + fo) = o;
    }
    __syncthreads();

    f32x4 acc[4][2];
    // GEMM1 (agg @ W1)
#pragma unroll
    for (int s = 0; s < 4; ++s)
#pragma unroll
        for (int t = 0; t < 2; ++t) acc[s][t] = (f32x4){0.f, 0.f, 0.f, 0.f};
#pragma unroll
    for (int kt = 0; kt < 4; ++kt) {
        const int ko = kt * 32 + q * 8;
        half8 a0 = *(const half8*)(Ab + (0 * 16 + l15) * 136 + ko);
        half8 a1 = *(const half8*)(Ab + (1 * 16 + l15) * 136 + ko);
        half8 a2 = *(const half8*)(Ab + (2 * 16 + l15) * 136 + ko);
        half8 a3 = *(const half8*)(Ab + (3 * 16 + l15) * 136 + ko);
        acc[0][0] = mfma16(a0, Bf[0][kt], acc[0][0]);
        acc[1][0] = mfma16(a1, Bf[0][kt], acc[1][0]);
        acc[2][0] = mfma16(a2, Bf[0][kt], acc[2][0]);
        acc[3][0] = mfma16(a3, Bf[0][kt], acc[3][0]);
        acc[0][1] = mfma16(a0, Bf[1][kt], acc[0][1]);
        acc[1][1] = mfma16(a1, Bf[1][kt], acc[1][1]);
        acc[2][1] = mfma16(a2, Bf[1][kt], acc[2][1]);
        acc[3][1] = mfma16(a3, Bf[1][kt], acc[3][1]);
    }
#pragma unroll
    for (int t = 0; t < 2; ++t)
#pragma unroll
        for (int kt = 0; kt < 4; ++kt)
            Bf[t][kt] = *(const half8*)(Wt2 + (wave * 32 + t * 16 + l15) * 128 + kt * 32 + q * 8);
    __syncthreads();
    // BN+relu -> Ab
#pragma unroll
    for (int t = 0; t < 2; ++t) {
        const int col = wave * 32 + t * 16 + l15;
        const float sc = A1[col], sh = B1[col];
#pragma unroll
        for (int s = 0; s < 4; ++s)
#pragma unroll
            for (int r = 0; r < 4; ++r) {
                const int row = s * 16 + q * 4 + r;
                float v = acc[s][t][r] * sc + sh;
                Ab[row * 136 + col] = (_Float16)fmaxf(v, 0.f);
            }
    }
    __syncthreads();

    // GEMM2 (Z @ W2)
#pragma unroll
    for (int s = 0; s < 4; ++s)
#pragma unroll
        for (int t = 0; t < 2; ++t) acc[s][t] = (f32x4){0.f, 0.f, 0.f, 0.f};
#pragma unroll
    for (int kt = 0; kt < 4; ++kt) {
        const int ko = kt * 32 + q * 8;
        half8 a0 = *(const half8*)(Ab + (0 * 16 + l15) * 136 + ko);
        half8 a1 = *(const half8*)(Ab + (1 * 16 + l15) * 136 + ko);
        half8 a2 = *(const half8*)(Ab + (2 * 16 + l15) * 136 + ko);
        half8 a3 = *(const half8*)(Ab + (3 * 16 + l15) * 136 + ko);
        acc[0][0] = mfma16(a0, Bf[0][kt], acc[0][0]);
        acc[1][0] = mfma16(a1, Bf[0][kt], acc[1][0]);
        acc[2][0] = mfma16(a2, Bf[0][kt], acc[2][0]);
        acc[3][0] = mfma16(a3, Bf[0][kt], acc[3][0]);
        acc[0][1] = mfma16(a0, Bf[1][kt], acc[0][1]);
        acc[1][1] = mfma16(a1, Bf[1][kt], acc[1][1]);
        acc[2][1] = mfma16(a2, Bf[1][kt], acc[2][1]);
        acc[3][1] = mfma16(a3, Bf[1][kt], acc[3][1]);
    }
#pragma unroll
    for (int t = 0; t < 2; ++t)
#pragma unroll
        for (int kt = 0; kt < 4; ++kt)
            Bf[t][kt] = *(const half8*)(lw1t + (wave * 32 + t * 16 + l15) * 128 + kt * 32 + q * 8);
    __syncthreads();
    // h3 = relu(acc + b2) -> Ab
#pragma unroll
    for (int t = 0; t < 2; ++t) {
        const int col = wave * 32 + t * 16 + l15;
        const float bb = b2[col];
#pragma unroll
        for (int s = 0; s < 4; ++s)
#pragma unroll
            for (int r = 0; r < 4; ++r) {
                const int row = s * 16 + q * 4 + r;
                Ab[row * 136 + col] = (_Float16)fmaxf(acc[s][t][r] + bb, 0.f);
            }
    }
    __syncthreads();

    // GEMM3 (h3 @ lw1)
#pragma unroll
    for (int s = 0; s < 4; ++s)
#pragma unroll
        for (int t = 0; t < 2; ++t) acc[s][t] = (f32x4){0.f, 0.f, 0.f, 0.f};
#pragma unroll
    for (int kt = 0; kt < 4; ++kt) {
        const int ko = kt * 32 + q * 8;
        half8 a0 = *(const half8*)(Ab + (0 * 16 + l15) * 136 + ko);
        half8 a1 = *(const half8*)(Ab + (1 * 16 + l15) * 136 + ko);
        half8 a2 = *(const half8*)(Ab + (2 * 16 + l15) * 136 + ko);
        half8 a3 = *(const half8*)(Ab + (3 * 16 + l15) * 136 + ko);
        acc[0][0] = mfma16(a0, Bf[0][kt], acc[0][0]);
        acc[1][0] = mfma16(a1, Bf[0][kt], acc[1][0]);
        acc[2][0] = mfma16(a2, Bf[0][kt], acc[2][0]);
        acc[3][0] = mfma16(a3, Bf[0][kt], acc[3][0]);
        acc[0][1] = mfma16(a0, Bf[1][kt], acc[0][1]);
        acc[1][1] = mfma16(a1, Bf[1][kt], acc[1][1]);
        acc[2][1] = mfma16(a2, Bf[1][kt], acc[2][1]);
        acc[3][1] = mfma16(a3, Bf[1][kt], acc[3][1]);
    }
    // preload GEMM4 B-fragments (48 valid rows; wave 3 idles)
    half8 Bh[4];
    if (wave < 3) {
#pragma unroll
        for (int kt = 0; kt < 4; ++kt)
            Bh[kt] = *(const half8*)(lw2t + (wave * 16 + l15) * 128 + kt * 32 + q * 8);
    }
    __syncthreads();
    // h4 = relu(acc + lb1) -> Ab
#pragma unroll
    for (int t = 0; t < 2; ++t) {
        const int col = wave * 32 + t * 16 + l15;
        const float bb = lb1[col];
#pragma unroll
        for (int s = 0; s < 4; ++s)
#pragma unroll
            for (int r = 0; r < 4; ++r) {
                const int row = s * 16 + q * 4 + r;
                Ab[row * 136 + col] = (_Float16)fmaxf(acc[s][t][r] + bb, 0.f);
            }
    }
    __syncthreads();

    // GEMM4 (h4 @ lw2, 48 cols, waves 0..2)
    f32x4 acc2[4];
#pragma unroll
    for (int s = 0; s < 4; ++s) acc2[s] = (f32x4){0.f, 0.f, 0.f, 0.f};
    if (wave < 3) {
#pragma unroll
        for (int kt = 0; kt < 4; ++kt) {
            const int ko = kt * 32 + q * 8;
            half8 a0 = *(const half8*)(Ab + (0 * 16 + l15) * 136 + ko);
            half8 a1 = *(const half8*)(Ab + (1 * 16 + l15) * 136 + ko);
            half8 a2 = *(const half8*)(Ab + (2 * 16 + l15) * 136 + ko);
            half8 a3 = *(const half8*)(Ab + (3 * 16 + l15) * 136 + ko);
            acc2[0] = mfma16(a0, Bh[kt], acc2[0]);
            acc2[1] = mfma16(a1, Bh[kt], acc2[1]);
            acc2[2] = mfma16(a2, Bh[kt], acc2[2]);
            acc2[3] = mfma16(a3, Bh[kt], acc2[3]);
        }
    }
    __syncthreads();  // all reads of Ab done before aliasing as float buffer

    float* Lb = (float*)Ab;  // 64 x 49 floats = 12.5 KB <= 17.4 KB
    if (wave < 3) {
        const int col = wave * 16 + l15;
        const float bb = (col < CC) ? lb2[col] : 0.f;
#pragma unroll
        for (int s = 0; s < 4; ++s)
#pragma unroll
            for (int r = 0; r < 4; ++r) {
                const int row = s * 16 + q * 4 + r;
                Lb[row * 49 + col] = acc2[s][r] + bb;
            }
    }
    __syncthreads();

    // log_softmax: one thread per row
    if (tid < 64) {
        const int g = tile0 + tid;
        if (g < NN) {
            float mx = -1e30f;
            for (int c = 0; c < CC; ++c) mx = fmaxf(mx, Lb[tid * 49 + c]);
            float ssum = 0.f;
            for (int c = 0; c < CC; ++c) ssum += expf(Lb[tid * 49 + c] - mx);
            const float ls = logf(ssum) + mx;
            for (int c = 0; c < CC; ++c) out[(size_t)g * CC + c] = Lb[tid * 49 + c] - ls;
        }
    }
}

// ---------------- host ----------------
extern "C" void kernel_launch(void* const* d_in, const int* in_sizes, int n_in,
                              void* d_out, int out_size, void* d_ws, size_t ws_size,
                              hipStream_t stream) {
    const float* x     = (const float*)d_in[0];
    const int*   ei    = (const int*)d_in[1];
    const float* W1    = (const float*)d_in[2];
    const float* b1    = (const float*)d_in[3];
    const float* gamma = (const float*)d_in[4];
    const float* beta  = (const float*)d_in[5];
    const float* bnm   = (const float*)d_in[6];
    const float* bnv   = (const float*)d_in[7];
    const float* W2    = (const float*)d_in[8];
    const float* b2    = (const float*)d_in[9];
    const float* lw1   = (const float*)d_in[10];
    const float* lb1   = (const float*)d_in[11];
    const float* lw2   = (const float*)d_in[12];
    const float* lb2   = (const float*)d_in[13];
    float* out = (float*)d_out;

    char* p = (char*)d_ws;
    auto carve = [&](size_t bytes) -> char* {
        char* r = p;
        p += (bytes + 255) & ~(size_t)255;
        return r;
    };
    int* deg      = (int*)carve((size_t)NN * 4);
    int* rowstart = (int*)carve((size_t)NN * 4);
    int* cursor   = (int*)carve((size_t)NN * 4);
    int* csr      = (int*)carve((size_t)EE * 4);
    int* blocksum = (int*)carve((size_t)SCAN_NB * 4);
    int* blockoff = (int*)carve((size_t)SCAN_NB * 4);
    _Float16* Wt1h = (_Float16*)carve((size_t)LL * HH * HH * 2);
    _Float16* Wt2h = (_Float16*)carve((size_t)LL * HH * HH * 2);
    _Float16* lw1t = (_Float16*)carve((size_t)HH * HH * 2);
    _Float16* lw2t = (_Float16*)carve((size_t)48 * HH * 2);
    float* A1f = (float*)carve((size_t)LL * HH * 4);
    float* B1f = (float*)carve((size_t)LL * HH * 4);
    _Float16* xh  = (_Float16*)carve((size_t)NN * HH * 2);
    _Float16* hb0 = (_Float16*)carve((size_t)NN * HH * 2);
    _Float16* hb1 = (_Float16*)carve((size_t)NN * HH * 2);

    // CSR build + prep
    hipMemsetAsync(deg, 0, (size_t)NN * 4, stream);
    const long prep_total = (long)NN * HH + 2L * LL * HH * HH + (long)HH * HH + 48L * HH + (long)LL * HH;
    const int prep_blocks = (int)((prep_total + 255) / 256);
    k_count_prep<<<CNT_B + prep_blocks, 256, 0, stream>>>(
        ei, deg, x, W1, W2, lw1, lw2, b1, gamma, beta, bnm, bnv,
        xh, Wt1h, Wt2h, lw1t, lw2t, A1f, B1f);
    k_blocksum<<<SCAN_NB, 256, 0, stream>>>(deg, blocksum);
    k_scanbs<<<1, 256, 0, stream>>>(blocksum, blockoff);
    k_apply<<<SCAN_NB, 256, 0, stream>>>(deg, blockoff, rowstart, cursor);
    k_fill<<<2048, 256, 0, stream>>>(ei, cursor, csr);

    // fused layers
    k_layer<<<NT_TILES, 256, 0, stream>>>(xh, hb0, Wt1h, Wt2h, A1f, B1f, b2,
                                          rowstart, deg, csr);
    k_layer<<<NT_TILES, 256, 0, stream>>>(hb0, hb1, Wt1h + HH * HH, Wt2h + HH * HH,
                                          A1f + HH, B1f + HH, b2 + HH,
                                          rowstart, deg, csr);
    k_layer_head<<<NT_TILES, 256, 0, stream>>>(hb1, Wt1h + 2 * HH * HH, Wt2h + 2 * HH * HH,
                                               A1f + 2 * HH, B1f + 2 * HH, b2 + 2 * HH,
                                               lw1t, lw2t, lb1, lb2, out,
                                               rowstart, deg, csr);
}